// Round 5
// baseline (1961.928 us; speedup 1.0000x reference)
//
#include <hip/hip_runtime.h>
#include <hip/hip_bf16.h>
#include <stdint.h>

typedef unsigned short u16;
typedef uint32_t u32;
typedef uint64_t u64;

#define NB 2
#define NA 8732
#define ND 604
#define NC 599
#define NM 300
#define NK 200
#define MT (NC * NM)     // 179700
#define NA4 (NA / 4)     // 2183
#define CONF 0.01f

// T preset: scores in (0.01,1) => f32 bits 31..26 are 001111 -> composite bits 45..40 = 01111
#define T_PRESET (0xFull << 40)

__device__ __forceinline__ float bf2f(u16 u) { return __uint_as_float(((u32)u) << 16); }

// meta[0] = input storage is true-bf16; meta[1]/meta[2] = per-batch kept counters.
__global__ void k_detect(const u16* __restrict__ in, u32* __restrict__ meta) {
  __shared__ u32 ws4[4], wz4[4];
  const int tid = threadIdx.x, lane = tid & 63, wid = tid >> 6;
  u32 ct = 0, cz = 0;
  for (int i = tid; i < 8192; i += 256) {
    const u16 v = in[i];
    ct += (u32)(v >> 15);
    cz += (u32)(((i & 1) == 0) && (v == 0));
  }
#pragma unroll
  for (int off = 32; off > 0; off >>= 1) {
    ct += __shfl_down(ct, off, 64);
    cz += __shfl_down(cz, off, 64);
  }
  if (lane == 0) { ws4[wid] = ct; wz4[wid] = cz; }
  __syncthreads();
  if (tid == 0) {
    const u32 tot_top = ws4[0] + ws4[1] + ws4[2] + ws4[3];
    const u32 tot_evz = wz4[0] + wz4[1] + wz4[2] + wz4[3];
    meta[0] = (tot_top == 0 && tot_evz < 1024) ? 1u : 0u;  // else f32 storage
    meta[1] = 0u; meta[2] = 0u; meta[3] = 0u;
  }
}

__global__ void k_zero_hist(u32* __restrict__ hist) {
  hist[blockIdx.x * 256 + threadIdx.x] = 0u;  // grid 512 x 256 = 131072 = 2*65536
}

// tiled transpose of class scores -> thresholded u32 keys [b][c][n] (coalesced both sides)
__global__ __launch_bounds__(256) void k_transpose_keys(const void* __restrict__ inv,
                                                        const u32* __restrict__ meta,
                                                        u32* __restrict__ keysT) {
  __shared__ u32 tile[64][65];
  const u32 isbf = meta[0];
  const int c0 = blockIdx.x * 64, n0 = blockIdx.y * 64, b = blockIdx.z;
  const int tj = threadIdx.x & 63, t4 = threadIdx.x >> 6;
  const u16* inh = (const u16*)inv;
  const float* inf_ = (const float*)inv;
#pragma unroll
  for (int kk = 0; kk < 16; ++kk) {
    const int i = t4 + kk * 4;
    const int n = n0 + i, c = c0 + tj;
    u32 kx = 0;
    if (n < NA && c < NC) {
      const size_t idx = (size_t)(b * NA + n) * ND + 1 + c;
      const float f = isbf ? bf2f(inh[idx]) : inf_[idx];
      kx = (f > CONF) ? __float_as_uint(f) : 0u;
    }
    tile[i][tj] = kx;
  }
  __syncthreads();
#pragma unroll
  for (int kk = 0; kk < 16; ++kk) {
    const int j = t4 + kk * 4;
    const int c = c0 + j, n = n0 + tj;
    if (c < NC && n < NA) keysT[(size_t)(b * NC + c) * NA + n] = tile[tj][j];
  }
}

// per-(b,c): exact stable top-300 (radix over unique composites) + greedy NMS,
// emitting kept entries as u64 (score32<<32 | (~flat18)<<14 | anchor14).
__global__ __launch_bounds__(256) void k_select_nms(const void* __restrict__ inv,
                                                    u32* __restrict__ meta,
                                                    u64* __restrict__ list,
                                                    const u32* __restrict__ keysT,
                                                    const int use_keys) {
  const int bc = blockIdx.x;
  const int b = bc / NC;
  const int c = bc - b * NC;
  const int tid = threadIdx.x;
  const int lane = tid & 63;
  const int wid = tid >> 6;

  __shared__ u32 wsum[4];
  __shared__ u64 cand[512];
  __shared__ u32 sh_cnt;

  const u32 isbf = meta[0];

  // key[e] = f32 bits of score if score > CONF else 0 (NaN -> 0).
  // composite = (key<<14) | (16383 - n): unique per anchor.
  u32 key[36];
  if (use_keys) {
    const uint4* col4 = (const uint4*)(keysT + (size_t)(b * NC + c) * NA);
#pragma unroll
    for (int r = 0; r < 9; ++r) {
      const int i4 = r * 256 + tid;
      if (i4 < NA4) {
        const uint4 k4 = col4[i4];
        key[r * 4 + 0] = k4.x; key[r * 4 + 1] = k4.y;
        key[r * 4 + 2] = k4.z; key[r * 4 + 3] = k4.w;
      } else {
        key[r * 4 + 0] = 0; key[r * 4 + 1] = 0; key[r * 4 + 2] = 0; key[r * 4 + 3] = 0;
      }
    }
  } else if (isbf) {
    const u16* basep = (const u16*)inv + (size_t)b * NA * ND + 1 + c;
#pragma unroll
    for (int r = 0; r < 9; ++r) {
      const int i4 = r * 256 + tid;
#pragma unroll
      for (int kk = 0; kk < 4; ++kk) {
        u32 kx = 0;
        if (i4 < NA4) {
          const float f = bf2f(basep[(size_t)(i4 * 4 + kk) * ND]);
          kx = (f > CONF) ? __float_as_uint(f) : 0u;
        }
        key[r * 4 + kk] = kx;
      }
    }
  } else {
    const float* basep = (const float*)inv + (size_t)b * NA * ND + 1 + c;
#pragma unroll
    for (int r = 0; r < 9; ++r) {
      const int i4 = r * 256 + tid;
#pragma unroll
      for (int kk = 0; kk < 4; ++kk) {
        u32 kx = 0;
        if (i4 < NA4) {
          const float f = basep[(size_t)(i4 * 4 + kk) * ND];
          kx = (f > CONF) ? __float_as_uint(f) : 0u;
        }
        key[r * 4 + kk] = kx;
      }
    }
  }

  auto blockSum = [&](u32 v) -> u32 {
#pragma unroll
    for (int off = 32; off > 0; off >>= 1) v += __shfl_down(v, off, 64);
    if (lane == 0) wsum[wid] = v;
    __syncthreads();
    const u32 tot = wsum[0] + wsum[1] + wsum[2] + wsum[3];
    __syncthreads();
    return tot;
  };

  // radix-max: T = 300th largest composite. Bits 45..40 preset (scores in (0.01,1)).
  // If a class has <300 above-conf entries, T stays at preset => only above-conf selected;
  // kept rows' ordering/flat indices are unaffected (below-conf rows never kept/suppress).
  u64 T = T_PRESET;
#pragma unroll 1
  for (int bit = 39; bit >= 0; --bit) {
    if (isbf && bit >= 14 && bit < 30) continue;  // true-bf16: score low-16 bits are 0
    const u64 T2 = T | (1ull << bit);
    const u32 Thi = (u32)(T2 >> 14);
    const u32 Tlo = (u32)(T2 & 0x3FFFu);
    u32 cnt = 0;
#pragma unroll
    for (int r = 0; r < 9; ++r) {
#pragma unroll
      for (int kk = 0; kk < 4; ++kk) {
        const u32 k = key[r * 4 + kk];
        const u32 nn = 16383u - (u32)((r * 256 + tid) * 4 + kk);
        cnt += (k > Thi || (k == Thi && nn >= Tlo)) ? 1u : 0u;
      }
    }
    if (blockSum(cnt) >= NM) T = T2;
  }

  // compact selected into cand[], bitonic-sort ascending (zeros pad the bottom)
  if (tid == 0) sh_cnt = 0;
  cand[tid] = 0; cand[tid + 256] = 0;
  __syncthreads();
  {
    const u32 Thi = (u32)(T >> 14);
    const u32 Tlo = (u32)(T & 0x3FFFu);
#pragma unroll
    for (int r = 0; r < 9; ++r) {
#pragma unroll
      for (int kk = 0; kk < 4; ++kk) {
        const u32 k = key[r * 4 + kk];
        const u32 nn = 16383u - (u32)((r * 256 + tid) * 4 + kk);
        if (k > Thi || (k == Thi && nn >= Tlo)) {
          const u32 p = atomicAdd(&sh_cnt, 1u);
          if (p < 512) cand[p] = (((u64)k) << 14) | (u64)nn;
        }
      }
    }
  }
  __syncthreads();

#pragma unroll 1
  for (u32 ks = 2; ks <= 512; ks <<= 1) {
#pragma unroll 1
    for (u32 j = ks >> 1; j > 0; j >>= 1) {
#pragma unroll
      for (int rep = 0; rep < 2; ++rep) {
        const u32 i = tid + rep * 256;
        const u32 ixj = i ^ j;
        if (ixj > i) {
          const u64 a = cand[i], bb = cand[ixj];
          const bool up = ((i & ks) == 0);
          if (up ? (a > bb) : (a < bb)) { cand[i] = bb; cand[ixj] = a; }
        }
      }
      __syncthreads();
    }
  }

  // wave 0: greedy NMS over the <=300 score-sorted candidates. _rn intrinsics prevent
  // FMA contraction diverging from the reference's rounded arithmetic.
  if (tid < 64) {
    float by0[5], bx0[5], by1[5], bx1[5], bar[5], bv[5];
    u32 bn[5];
    bool sup[5], keep[5];
#pragma unroll
    for (int q = 0; q < 5; ++q) {
      const int j = q * 64 + lane;
      keep[q] = false;
      by0[q] = bx0[q] = by1[q] = bx1[q] = bar[q] = 0.f;
      if (j < NM) {
        const u64 e = cand[511 - j];
        const u32 sb = (u32)(e >> 14);
        u32 n = 16383u - ((u32)e & 0x3FFFu);
        if (n >= (u32)NA) n = 0;      // zero-pad slot (class had <300 above-conf)
        sup[q] = false;
        bn[q] = n;
        bv[q] = __uint_as_float(sb);  // 0.0f for pad/below-conf
        float cx, cy, w, h;
        if (isbf) {
          const u16* bp = (const u16*)inv + (size_t)(b * NA + n) * ND + 600;
          const ushort4 ub = *(const ushort4*)bp;
          cx = bf2f(ub.x); cy = bf2f(ub.y); w = bf2f(ub.z); h = bf2f(ub.w);
        } else {
          const float* bp = (const float*)inv + (size_t)(b * NA + n) * ND + 600;
          const float4 f4 = *(const float4*)bp;
          cx = f4.x; cy = f4.y; w = f4.z; h = f4.w;
        }
        const float y0 = __fsub_rn(cy, __fmul_rn(h, 0.5f));
        const float x0 = __fsub_rn(cx, __fmul_rn(w, 0.5f));
        const float y1 = __fadd_rn(cy, __fmul_rn(h, 0.5f));
        const float x1 = __fadd_rn(cx, __fmul_rn(w, 0.5f));
        by0[q] = y0; bx0[q] = x0; by1[q] = y1; bx1[q] = x1;
        bar[q] = __fmul_rn(__fsub_rn(y1, y0), __fsub_rn(x1, x0));
      } else {
        bv[q] = 0.f; bn[q] = 0; sup[q] = true;
      }
    }
#pragma unroll
    for (int qi = 0; qi < 5; ++qi) {
      const int lim = (qi == 4) ? (NM - 256) : 64;
#pragma unroll 1
      for (int li = 0; li < lim; ++li) {
        const int kq = (!sup[qi] && bv[qi] > CONF) ? 1 : 0;
        const int ki = __shfl(kq, li, 64);
        if (lane == li) keep[qi] = (ki != 0);
        if (ki) {
          const float iy0 = __shfl(by0[qi], li, 64);
          const float ix0 = __shfl(bx0[qi], li, 64);
          const float iy1 = __shfl(by1[qi], li, 64);
          const float ix1 = __shfl(bx1[qi], li, 64);
          const float iar = __shfl(bar[qi], li, 64);
          const int i = qi * 64 + li;
#pragma unroll
          for (int q = 0; q < 5; ++q) {
            const int j = q * 64 + lane;
            if (j > i && j < NM && !sup[q]) {
              const float ih = fmaxf(__fsub_rn(fminf(iy1, by1[q]), fmaxf(iy0, by0[q])), 0.f);
              const float iw = fmaxf(__fsub_rn(fminf(ix1, bx1[q]), fmaxf(ix0, bx0[q])), 0.f);
              const float inter = __fmul_rn(ih, iw);
              const float uni = __fsub_rn(__fadd_rn(iar, bar[q]), inter);
              if (uni > 0.f && __fdiv_rn(inter, uni) > 0.45f) sup[q] = true;
            }
          }
        }
      }
    }
#pragma unroll
    for (int q = 0; q < 5; ++q) {
      const int j = q * 64 + lane;
      if (j < NM && keep[q]) {
        const u32 p = atomicAdd(&meta[1 + b], 1u);
        const u32 flat = (u32)c * NM + (u32)j;
        if (p < (u32)MT)
          list[(size_t)b * MT + p] = (((u64)__float_as_uint(bv[q])) << 32)
                                   | (((u64)(0x3FFFFu - flat)) << 14)
                                   | (u64)bn[q];
      }
    }
  }
}

// parallel histogram over score top-16 bits
__global__ __launch_bounds__(256) void k_hist(const u64* __restrict__ list,
                                              const u32* __restrict__ meta,
                                              u32* __restrict__ hist) {
  const u32 idx = blockIdx.x * 256 + threadIdx.x;
  if (idx < (u32)(NB * MT)) {
    const u32 b = idx < (u32)MT ? 0u : 1u;
    const u32 j = idx - b * MT;
    if (j < meta[1 + b])
      atomicAdd(&hist[(size_t)b * 65536 + (u32)(list[idx] >> 48)], 1u);
  }
}

// shared epilogue: corner->center transform + dtype-matched store
__device__ __forceinline__ void emit_row(const void* inv, u32 isbf, int b, int tid,
                                         u64 e, void* outv) {
  float o0 = 0, o1 = 0, o2 = 0, o3 = 0, o4 = 0, o5 = 0;
  if (e != 0) {
    const u32 sb = (u32)(e >> 32);
    const u32 flat = 0x3FFFFu - ((u32)(e >> 14) & 0x3FFFFu);
    const u32 anchor = (u32)e & 0x3FFFu;
    const u32 cls = flat / NM;
    float cx, cy, w, h;
    if (isbf) {
      const u16* bp = (const u16*)inv + (size_t)(b * NA + anchor) * ND + 600;
      const ushort4 ub = *(const ushort4*)bp;
      cx = bf2f(ub.x); cy = bf2f(ub.y); w = bf2f(ub.z); h = bf2f(ub.w);
    } else {
      const float* bp = (const float*)inv + (size_t)(b * NA + anchor) * ND + 600;
      const float4 f4 = *(const float4*)bp;
      cx = f4.x; cy = f4.y; w = f4.z; h = f4.w;
    }
    const float y0 = __fsub_rn(cy, __fmul_rn(h, 0.5f));
    const float x0 = __fsub_rn(cx, __fmul_rn(w, 0.5f));
    const float y1 = __fadd_rn(cy, __fmul_rn(h, 0.5f));
    const float x1 = __fadd_rn(cx, __fmul_rn(w, 0.5f));
    const float th = __fsub_rn(y1, y0), tw = __fsub_rn(x1, x0);
    o0 = (float)(cls + 1);
    o1 = __uint_as_float(sb);
    o2 = __fadd_rn(x0, __fmul_rn(tw, 0.5f));
    o3 = __fadd_rn(y0, __fmul_rn(th, 0.5f));
    o4 = tw;
    o5 = th;
  }
  if (isbf) {
    __hip_bfloat16* op = (__hip_bfloat16*)outv + ((size_t)b * NK + tid) * 6;
    op[0] = __float2bfloat16(o0); op[1] = __float2bfloat16(o1);
    op[2] = __float2bfloat16(o2); op[3] = __float2bfloat16(o3);
    op[4] = __float2bfloat16(o4); op[5] = __float2bfloat16(o5);
  } else {
    float* op = (float*)outv + ((size_t)b * NK + tid) * 6;
    op[0] = o0; op[1] = o1; op[2] = o2; op[3] = o3; op[4] = o4; op[5] = o5;
  }
}

// per batch: histogram-guided exact top-200. One list pass + sort of <=512 candidates.
__global__ __launch_bounds__(1024) void k_topk_hist(const void* __restrict__ inv,
                                                    const u32* __restrict__ meta,
                                                    const u64* __restrict__ list,
                                                    const u32* __restrict__ hist,
                                                    void* __restrict__ outv) {
  const int b = blockIdx.x, tid = threadIdx.x, lane = tid & 63, wid = tid >> 6;
  const u32 isbf = meta[0];
  u32 nb = meta[1 + b];
  if (nb > (u32)MT) nb = (u32)MT;
  const u64* lb = list + (size_t)b * MT;
  const u32* hh = hist + (size_t)b * 65536;

  __shared__ u32 ps[1024];
  __shared__ u64 sel[512];
  __shared__ u32 wsum[16];
  __shared__ u32 sh_T16, sh_cc;

  // per-thread sums of 64 contiguous bins (uint4 loads)
  {
    const uint4* h4 = (const uint4*)(hh + tid * 64);
    u32 s = 0;
#pragma unroll
    for (int j = 0; j < 16; ++j) {
      const uint4 v = h4[j];
      s += v.x + v.y + v.z + v.w;
    }
    ps[tid] = s;
  }
  if (tid == 0) { sh_cc = 0; sh_T16 = 0; }
  __syncthreads();
  if (tid == 0) {
    u32 acc = 0; int tb = -1;
    for (int t = 1023; t >= 0; --t) {
      if (acc + ps[t] >= (u32)NK) { tb = t; break; }
      acc += ps[t];
    }
    u32 T16 = 0;
    if (tb >= 0) {
      for (int j = 63; j >= 0; --j) {
        const u32 cc2 = hh[tb * 64 + j];
        if (acc + cc2 >= (u32)NK) { T16 = (u32)(tb * 64 + j); break; }
        acc += cc2;
      }
    }
    sh_T16 = T16;   // total < 200 => T16 = 0 => collect everything
  }
  __syncthreads();
  const u32 T16 = sh_T16;

  for (u32 i = tid; i < nb; i += 1024) {
    const u64 e = lb[i];
    if ((u32)(e >> 48) >= T16) {
      const u32 p = atomicAdd(&sh_cc, 1u);
      if (p < 512) sel[p] = e;
    }
  }
  __syncthreads();
  u32 cc = sh_cc;

  if (cc > 512) {
    // pathological tie density: exact global radix fallback (rare)
    auto bsum = [&](u32 v) -> u32 {
#pragma unroll
      for (int off = 32; off > 0; off >>= 1) v += __shfl_down(v, off, 64);
      if (lane == 0) wsum[wid] = v;
      __syncthreads();
      u32 t = 0;
#pragma unroll
      for (int wq = 0; wq < 16; ++wq) t += wsum[wq];
      __syncthreads();
      return t;
    };
    u64 T = 0;
#pragma unroll 1
    for (int bit = 47; bit >= 0; --bit) {
      if (isbf && bit >= 18 && bit < 34) continue;
      const u64 T2 = T | (1ull << bit);
      u32 cn = 0;
      for (u32 i = tid; i < nb; i += 1024) cn += ((lb[i] >> 14) >= T2) ? 1u : 0u;
      if (bsum(cn) >= (u32)NK) T = T2;
    }
    __syncthreads();
    if (tid == 0) sh_cc = 0;
    __syncthreads();
    for (u32 i = tid; i < nb; i += 1024) {
      if ((lb[i] >> 14) >= T) {
        const u32 p = atomicAdd(&sh_cc, 1u);
        if (p < 512) sel[p] = lb[i];
      }
    }
    __syncthreads();
    cc = sh_cc;
  }

  for (u32 p = cc + tid; p < 512; p += 1024) sel[p] = 0;
  __syncthreads();

#pragma unroll 1
  for (u32 ks = 2; ks <= 512; ks <<= 1) {
#pragma unroll 1
    for (u32 j = ks >> 1; j > 0; j >>= 1) {
      if (tid < 512) {
        const u32 i = (u32)tid, ixj = i ^ j;
        if (ixj > i) {
          const u64 a = sel[i], c2 = sel[ixj];
          const bool up = ((i & ks) == 0);
          if (up ? (a > c2) : (a < c2)) { sel[i] = c2; sel[ixj] = a; }
        }
      }
      __syncthreads();
    }
  }

  if (tid < NK) emit_row(inv, isbf, b, tid, sel[511 - tid], outv);
}

// fallback (tiny workspace): exact top-200 via capless radix over the global list
__global__ __launch_bounds__(1024) void k_topk_radix(const void* __restrict__ inv,
                                                     const u32* __restrict__ meta,
                                                     const u64* __restrict__ list,
                                                     void* __restrict__ outv) {
  const int b = blockIdx.x, tid = threadIdx.x, lane = tid & 63, wid = tid >> 6;
  const u32 isbf = meta[0];
  u32 nb = meta[1 + b];
  if (nb > (u32)MT) nb = (u32)MT;
  const u64* lb = list + (size_t)b * MT;

  __shared__ u64 sel[256];
  __shared__ u32 wsum[16];
  __shared__ u32 sh_ss;

  if (tid == 0) sh_ss = 0;
  __syncthreads();

  auto bsum = [&](u32 v) -> u32 {
#pragma unroll
    for (int off = 32; off > 0; off >>= 1) v += __shfl_down(v, off, 64);
    if (lane == 0) wsum[wid] = v;
    __syncthreads();
    u32 t = 0;
#pragma unroll
    for (int wq = 0; wq < 16; ++wq) t += wsum[wq];
    __syncthreads();
    return t;
  };

  u64 T = 0;
  if (nb > (u32)NK) {
#pragma unroll 1
    for (int bit = 47; bit >= 0; --bit) {
      if (isbf && bit >= 18 && bit < 34) continue;
      const u64 T2 = T | (1ull << bit);
      u32 cn = 0;
      for (u32 i = tid; i < nb; i += 1024) cn += ((lb[i] >> 14) >= T2) ? 1u : 0u;
      if (bsum(cn) >= (u32)NK) T = T2;
    }
  }

  for (u32 i = tid; i < nb; i += 1024) {
    if ((lb[i] >> 14) >= T) {
      const u32 p = atomicAdd(&sh_ss, 1u);
      if (p < 256) sel[p] = lb[i];
    }
  }
  __syncthreads();
  u32 tot = sh_ss; if (tot > 256) tot = 256;
  for (u32 p = tot + tid; p < 256; p += 1024) sel[p] = 0;
  __syncthreads();

#pragma unroll 1
  for (u32 ks = 2; ks <= 256; ks <<= 1) {
#pragma unroll 1
    for (u32 j = ks >> 1; j > 0; j >>= 1) {
      if (tid < 256) {
        const u32 i = (u32)tid, ixj = i ^ j;
        if (ixj > i) {
          const u64 a = sel[i], c2 = sel[ixj];
          const bool up = ((i & ks) == 0);
          if (up ? (a > c2) : (a < c2)) { sel[i] = c2; sel[ixj] = a; }
        }
      }
      __syncthreads();
    }
  }

  if (tid < NK) emit_row(inv, isbf, b, tid, sel[255 - tid], outv);
}

extern "C" void kernel_launch(void* const* d_in, const int* in_sizes, int n_in,
                              void* d_out, int out_size, void* d_ws, size_t ws_size,
                              hipStream_t stream) {
  (void)in_sizes; (void)n_in; (void)out_size;
  const void* in = d_in[0];
  char* ws = (char*)d_ws;

  // layout: meta u32[8] @0 | list u64[2*MT] @32 (2,875,200) | hist u32[2*65536] @2,875,232
  //         (524,288) | keysT u32[2*NC*NA] @3,399,520 (41,843,744) => 45,243,264 total
  u32* meta = (u32*)ws;
  u64* list = (u64*)(ws + 32);
  u32* hist = (u32*)(ws + 2875232);
  u32* keysT = (u32*)(ws + 3399520);
  const bool tier1 = ws_size >= 45243264u;   // transpose + hist
  const bool tier2 = ws_size >= 3399520u;    // hist only

  hipLaunchKernelGGL(k_detect, dim3(1), dim3(256), 0, stream, (const u16*)in, meta);
  if (tier2) hipLaunchKernelGGL(k_zero_hist, dim3(512), dim3(256), 0, stream, hist);
  if (tier1) hipLaunchKernelGGL(k_transpose_keys, dim3(10, 137, 2), dim3(256), 0, stream,
                                in, meta, keysT);
  hipLaunchKernelGGL(k_select_nms, dim3(NB * NC), dim3(256), 0, stream,
                     in, meta, list, keysT, tier1 ? 1 : 0);
  if (tier2) {
    hipLaunchKernelGGL(k_hist, dim3((NB * MT + 255) / 256), dim3(256), 0, stream,
                       list, meta, hist);
    hipLaunchKernelGGL(k_topk_hist, dim3(NB), dim3(1024), 0, stream,
                       in, meta, list, hist, d_out);
  } else {
    hipLaunchKernelGGL(k_topk_radix, dim3(NB), dim3(1024), 0, stream,
                       in, meta, list, d_out);
  }
}

// Round 6
// 1613.167 us; speedup vs baseline: 1.2162x; 1.2162x over previous
//
#include <hip/hip_runtime.h>
#include <hip/hip_bf16.h>
#include <stdint.h>

typedef unsigned short u16;
typedef uint32_t u32;
typedef uint64_t u64;

#define NB 2
#define NA 8732
#define ND 604
#define NC 599
#define NM 300
#define NK 200
#define MT (NC * NM)     // 179700
#define NA4 (NA / 4)     // 2183
#define CONF 0.01f
#define NBIN 4096

// T preset: scores in (0.01,1) => f32 bits 31..26 are 001111 -> composite bits 45..40 = 01111
#define T_PRESET (0xFull << 40)

__device__ __forceinline__ float bf2f(u16 u) { return __uint_as_float(((u32)u) << 16); }

// value-uniform score bin; monotone in score, identical arithmetic at emit & collect
__device__ __forceinline__ u32 binOf(u32 sbits) {
  const u32 bin = (u32)__fmul_rn(__uint_as_float(sbits), 4096.0f);
  return bin > (NBIN - 1) ? (NBIN - 1) : bin;
}

// meta[0] = input storage is true-bf16. Also zeroes the per-batch score histogram.
__global__ void k_detect(const u16* __restrict__ in, u32* __restrict__ meta,
                         u32* __restrict__ hist) {
  __shared__ u32 ws4[4], wz4[4];
  const int tid = threadIdx.x, lane = tid & 63, wid = tid >> 6;
  u32 ct = 0, cz = 0;
  for (int i = tid; i < 8192; i += 256) {
    const u16 v = in[i];
    ct += (u32)(v >> 15);
    cz += (u32)(((i & 1) == 0) && (v == 0));
  }
  for (int i = tid; i < NB * NBIN; i += 256) hist[i] = 0u;  // zero histogram (ws is 0xAA-poisoned)
#pragma unroll
  for (int off = 32; off > 0; off >>= 1) {
    ct += __shfl_down(ct, off, 64);
    cz += __shfl_down(cz, off, 64);
  }
  if (lane == 0) { ws4[wid] = ct; wz4[wid] = cz; }
  __syncthreads();
  if (tid == 0) {
    const u32 tot_top = ws4[0] + ws4[1] + ws4[2] + ws4[3];
    const u32 tot_evz = wz4[0] + wz4[1] + wz4[2] + wz4[3];
    meta[0] = (tot_top == 0 && tot_evz < 1024) ? 1u : 0u;  // else f32 storage
    meta[1] = 0u; meta[2] = 0u; meta[3] = 0u;
  }
}

// tiled transpose of class scores -> thresholded u32 keys [b][c][n] (coalesced both sides)
__global__ __launch_bounds__(256) void k_transpose_keys(const void* __restrict__ inv,
                                                        const u32* __restrict__ meta,
                                                        u32* __restrict__ keysT) {
  __shared__ u32 tile[64][65];
  const u32 isbf = meta[0];
  const int c0 = blockIdx.x * 64, n0 = blockIdx.y * 64, b = blockIdx.z;
  const int tj = threadIdx.x & 63, t4 = threadIdx.x >> 6;
  const u16* inh = (const u16*)inv;
  const float* inf_ = (const float*)inv;
#pragma unroll
  for (int kk = 0; kk < 16; ++kk) {
    const int i = t4 + kk * 4;
    const int n = n0 + i, c = c0 + tj;
    u32 kx = 0;
    if (n < NA && c < NC) {
      const size_t idx = (size_t)(b * NA + n) * ND + 1 + c;
      const float f = isbf ? bf2f(inh[idx]) : inf_[idx];
      kx = (f > CONF) ? __float_as_uint(f) : 0u;
    }
    tile[i][tj] = kx;
  }
  __syncthreads();
#pragma unroll
  for (int kk = 0; kk < 16; ++kk) {
    const int j = t4 + kk * 4;
    const int c = c0 + j, n = n0 + tj;
    if (c < NC && n < NA) keysT[(size_t)(b * NC + c) * NA + n] = tile[tj][j];
  }
}

// per-(b,c): exact stable top-300 (radix over unique composites) + greedy NMS.
// Kept entries land at FIXED slots list[b*MT + c*NM + rank] (0 if not kept) -- no
// global counter, fully coalesced stores. Also feeds the value-binned histogram
// (~50 scattered atomics/block over 4096 bins: no cache-line hotspots).
__global__ __launch_bounds__(256) void k_select_nms(const void* __restrict__ inv,
                                                    const u32* __restrict__ meta,
                                                    u64* __restrict__ list,
                                                    u32* __restrict__ hist,
                                                    const u32* __restrict__ keysT,
                                                    const int use_keys) {
  const int bc = blockIdx.x;
  const int b = bc / NC;
  const int c = bc - b * NC;
  const int tid = threadIdx.x;
  const int lane = tid & 63;
  const int wid = tid >> 6;

  __shared__ u32 wsum[4];
  __shared__ u64 cand[512];
  __shared__ u32 sh_cnt;

  const u32 isbf = meta[0];

  // key[e] = f32 bits of score if score > CONF else 0 (NaN -> 0).
  // composite = (key<<14) | (16383 - n): unique per anchor.
  u32 key[36];
  if (use_keys) {
    const uint4* col4 = (const uint4*)(keysT + (size_t)(b * NC + c) * NA);
#pragma unroll
    for (int r = 0; r < 9; ++r) {
      const int i4 = r * 256 + tid;
      if (i4 < NA4) {
        const uint4 k4 = col4[i4];
        key[r * 4 + 0] = k4.x; key[r * 4 + 1] = k4.y;
        key[r * 4 + 2] = k4.z; key[r * 4 + 3] = k4.w;
      } else {
        key[r * 4 + 0] = 0; key[r * 4 + 1] = 0; key[r * 4 + 2] = 0; key[r * 4 + 3] = 0;
      }
    }
  } else if (isbf) {
    const u16* basep = (const u16*)inv + (size_t)b * NA * ND + 1 + c;
#pragma unroll
    for (int r = 0; r < 9; ++r) {
      const int i4 = r * 256 + tid;
#pragma unroll
      for (int kk = 0; kk < 4; ++kk) {
        u32 kx = 0;
        if (i4 < NA4) {
          const float f = bf2f(basep[(size_t)(i4 * 4 + kk) * ND]);
          kx = (f > CONF) ? __float_as_uint(f) : 0u;
        }
        key[r * 4 + kk] = kx;
      }
    }
  } else {
    const float* basep = (const float*)inv + (size_t)b * NA * ND + 1 + c;
#pragma unroll
    for (int r = 0; r < 9; ++r) {
      const int i4 = r * 256 + tid;
#pragma unroll
      for (int kk = 0; kk < 4; ++kk) {
        u32 kx = 0;
        if (i4 < NA4) {
          const float f = basep[(size_t)(i4 * 4 + kk) * ND];
          kx = (f > CONF) ? __float_as_uint(f) : 0u;
        }
        key[r * 4 + kk] = kx;
      }
    }
  }

  auto blockSum = [&](u32 v) -> u32 {
#pragma unroll
    for (int off = 32; off > 0; off >>= 1) v += __shfl_down(v, off, 64);
    if (lane == 0) wsum[wid] = v;
    __syncthreads();
    const u32 tot = wsum[0] + wsum[1] + wsum[2] + wsum[3];
    __syncthreads();
    return tot;
  };

  // radix-max: T = 300th largest composite. Bits 45..40 preset (scores in (0.01,1)).
  u64 T = T_PRESET;
#pragma unroll 1
  for (int bit = 39; bit >= 0; --bit) {
    if (isbf && bit >= 14 && bit < 30) continue;  // true-bf16: score low-16 bits are 0
    const u64 T2 = T | (1ull << bit);
    const u32 Thi = (u32)(T2 >> 14);
    const u32 Tlo = (u32)(T2 & 0x3FFFu);
    u32 cnt = 0;
#pragma unroll
    for (int r = 0; r < 9; ++r) {
#pragma unroll
      for (int kk = 0; kk < 4; ++kk) {
        const u32 k = key[r * 4 + kk];
        const u32 nn = 16383u - (u32)((r * 256 + tid) * 4 + kk);
        cnt += (k > Thi || (k == Thi && nn >= Tlo)) ? 1u : 0u;
      }
    }
    if (blockSum(cnt) >= NM) T = T2;
  }

  // compact selected into cand[], bitonic-sort ascending (zeros pad the bottom)
  if (tid == 0) sh_cnt = 0;
  cand[tid] = 0; cand[tid + 256] = 0;
  __syncthreads();
  {
    const u32 Thi = (u32)(T >> 14);
    const u32 Tlo = (u32)(T & 0x3FFFu);
#pragma unroll
    for (int r = 0; r < 9; ++r) {
#pragma unroll
      for (int kk = 0; kk < 4; ++kk) {
        const u32 k = key[r * 4 + kk];
        const u32 nn = 16383u - (u32)((r * 256 + tid) * 4 + kk);
        if (k > Thi || (k == Thi && nn >= Tlo)) {
          const u32 p = atomicAdd(&sh_cnt, 1u);
          if (p < 512) cand[p] = (((u64)k) << 14) | (u64)nn;
        }
      }
    }
  }
  __syncthreads();

#pragma unroll 1
  for (u32 ks = 2; ks <= 512; ks <<= 1) {
#pragma unroll 1
    for (u32 j = ks >> 1; j > 0; j >>= 1) {
#pragma unroll
      for (int rep = 0; rep < 2; ++rep) {
        const u32 i = tid + rep * 256;
        const u32 ixj = i ^ j;
        if (ixj > i) {
          const u64 a = cand[i], bb = cand[ixj];
          const bool up = ((i & ks) == 0);
          if (up ? (a > bb) : (a < bb)) { cand[i] = bb; cand[ixj] = a; }
        }
      }
      __syncthreads();
    }
  }

  // wave 0: greedy NMS over the <=300 score-sorted candidates. _rn intrinsics prevent
  // FMA contraction diverging from the reference's rounded arithmetic.
  if (tid < 64) {
    float by0[5], bx0[5], by1[5], bx1[5], bar[5], bv[5];
    u32 bn[5];
    bool sup[5], keep[5];
#pragma unroll
    for (int q = 0; q < 5; ++q) {
      const int j = q * 64 + lane;
      keep[q] = false;
      by0[q] = bx0[q] = by1[q] = bx1[q] = bar[q] = 0.f;
      if (j < NM) {
        const u64 e = cand[511 - j];
        const u32 sb = (u32)(e >> 14);
        u32 n = 16383u - ((u32)e & 0x3FFFu);
        if (n >= (u32)NA) n = 0;      // zero-pad slot (class had <300 above-conf)
        sup[q] = false;
        bn[q] = n;
        bv[q] = __uint_as_float(sb);  // 0.0f for pad/below-conf
        float cx, cy, w, h;
        if (isbf) {
          const u16* bp = (const u16*)inv + (size_t)(b * NA + n) * ND + 600;
          const ushort4 ub = *(const ushort4*)bp;
          cx = bf2f(ub.x); cy = bf2f(ub.y); w = bf2f(ub.z); h = bf2f(ub.w);
        } else {
          const float* bp = (const float*)inv + (size_t)(b * NA + n) * ND + 600;
          const float4 f4 = *(const float4*)bp;
          cx = f4.x; cy = f4.y; w = f4.z; h = f4.w;
        }
        const float y0 = __fsub_rn(cy, __fmul_rn(h, 0.5f));
        const float x0 = __fsub_rn(cx, __fmul_rn(w, 0.5f));
        const float y1 = __fadd_rn(cy, __fmul_rn(h, 0.5f));
        const float x1 = __fadd_rn(cx, __fmul_rn(w, 0.5f));
        by0[q] = y0; bx0[q] = x0; by1[q] = y1; bx1[q] = x1;
        bar[q] = __fmul_rn(__fsub_rn(y1, y0), __fsub_rn(x1, x0));
      } else {
        bv[q] = 0.f; bn[q] = 0; sup[q] = true;
      }
    }
#pragma unroll
    for (int qi = 0; qi < 5; ++qi) {
      const int lim = (qi == 4) ? (NM - 256) : 64;
#pragma unroll 1
      for (int li = 0; li < lim; ++li) {
        const int kq = (!sup[qi] && bv[qi] > CONF) ? 1 : 0;
        const int ki = __shfl(kq, li, 64);
        if (lane == li) keep[qi] = (ki != 0);
        if (ki) {
          const float iy0 = __shfl(by0[qi], li, 64);
          const float ix0 = __shfl(bx0[qi], li, 64);
          const float iy1 = __shfl(by1[qi], li, 64);
          const float ix1 = __shfl(bx1[qi], li, 64);
          const float iar = __shfl(bar[qi], li, 64);
          const int i = qi * 64 + li;
#pragma unroll
          for (int q = 0; q < 5; ++q) {
            const int j = q * 64 + lane;
            if (j > i && j < NM && !sup[q]) {
              const float ih = fmaxf(__fsub_rn(fminf(iy1, by1[q]), fmaxf(iy0, by0[q])), 0.f);
              const float iw = fmaxf(__fsub_rn(fminf(ix1, bx1[q]), fmaxf(ix0, bx0[q])), 0.f);
              const float inter = __fmul_rn(ih, iw);
              const float uni = __fsub_rn(__fadd_rn(iar, bar[q]), inter);
              if (uni > 0.f && __fdiv_rn(inter, uni) > 0.45f) sup[q] = true;
            }
          }
        }
      }
    }
    // fixed-slot emission: coalesced, no global counter
#pragma unroll
    for (int q = 0; q < 5; ++q) {
      const int j = q * 64 + lane;
      if (j < NM) {
        u64 entry = 0;
        if (keep[q]) {
          const u32 sb = __float_as_uint(bv[q]);
          const u32 flat = (u32)c * NM + (u32)j;
          entry = (((u64)sb) << 32) | (((u64)(0x3FFFFu - flat)) << 14) | (u64)bn[q];
          atomicAdd(&hist[(size_t)b * NBIN + binOf(sb)], 1u);
        }
        list[(size_t)b * MT + (u32)c * NM + (u32)j] = entry;
      }
    }
  }
}

// shared epilogue: corner->center transform + dtype-matched store
__device__ __forceinline__ void emit_row(const void* inv, u32 isbf, int b, int tid,
                                         u64 e, void* outv) {
  float o0 = 0, o1 = 0, o2 = 0, o3 = 0, o4 = 0, o5 = 0;
  if (e != 0) {
    const u32 sb = (u32)(e >> 32);
    const u32 flat = 0x3FFFFu - ((u32)(e >> 14) & 0x3FFFFu);
    const u32 anchor = (u32)e & 0x3FFFu;
    const u32 cls = flat / NM;
    float cx, cy, w, h;
    if (isbf) {
      const u16* bp = (const u16*)inv + (size_t)(b * NA + anchor) * ND + 600;
      const ushort4 ub = *(const ushort4*)bp;
      cx = bf2f(ub.x); cy = bf2f(ub.y); w = bf2f(ub.z); h = bf2f(ub.w);
    } else {
      const float* bp = (const float*)inv + (size_t)(b * NA + anchor) * ND + 600;
      const float4 f4 = *(const float4*)bp;
      cx = f4.x; cy = f4.y; w = f4.z; h = f4.w;
    }
    const float y0 = __fsub_rn(cy, __fmul_rn(h, 0.5f));
    const float x0 = __fsub_rn(cx, __fmul_rn(w, 0.5f));
    const float y1 = __fadd_rn(cy, __fmul_rn(h, 0.5f));
    const float x1 = __fadd_rn(cx, __fmul_rn(w, 0.5f));
    const float th = __fsub_rn(y1, y0), tw = __fsub_rn(x1, x0);
    o0 = (float)(cls + 1);
    o1 = __uint_as_float(sb);
    o2 = __fadd_rn(x0, __fmul_rn(tw, 0.5f));
    o3 = __fadd_rn(y0, __fmul_rn(th, 0.5f));
    o4 = tw;
    o5 = th;
  }
  if (isbf) {
    __hip_bfloat16* op = (__hip_bfloat16*)outv + ((size_t)b * NK + tid) * 6;
    op[0] = __float2bfloat16(o0); op[1] = __float2bfloat16(o1);
    op[2] = __float2bfloat16(o2); op[3] = __float2bfloat16(o3);
    op[4] = __float2bfloat16(o4); op[5] = __float2bfloat16(o5);
  } else {
    float* op = (float*)outv + ((size_t)b * NK + tid) * 6;
    op[0] = o0; op[1] = o1; op[2] = o2; op[3] = o3; op[4] = o4; op[5] = o5;
  }
}

// per batch: histogram-guided exact top-200 over the fixed-slot list.
__global__ __launch_bounds__(1024) void k_topk(const void* __restrict__ inv,
                                               const u32* __restrict__ meta,
                                               const u64* __restrict__ list,
                                               const u32* __restrict__ hist,
                                               void* __restrict__ outv) {
  const int b = blockIdx.x, tid = threadIdx.x, lane = tid & 63, wid = tid >> 6;
  const u32 isbf = meta[0];
  const u64* lb = list + (size_t)b * MT;
  const u32* hh = hist + (size_t)b * NBIN;

  __shared__ u32 ps[1024];
  __shared__ u64 sel[512];
  __shared__ u32 wsum[16];
  __shared__ u32 sh_B, sh_cc;

  {
    const uint4 hv = ((const uint4*)hh)[tid];
    ps[tid] = hv.x + hv.y + hv.z + hv.w;
  }
  if (tid == 0) { sh_cc = 0; sh_B = 0; }
  __syncthreads();
  if (tid == 0) {
    u32 acc = 0, B = 0;
    for (int t = 1023; t >= 0; --t) {
      if (acc + ps[t] >= (u32)NK) {
        u32 a2 = acc;
        for (int jj = 3; jj >= 0; --jj) {
          const u32 cb = hh[t * 4 + jj];
          if (a2 + cb >= (u32)NK) { B = (u32)(t * 4 + jj); break; }
          a2 += cb;
        }
        break;
      }
      acc += ps[t];
    }
    sh_B = B;   // total kept < 200 => B = 0 => collect everything
  }
  __syncthreads();
  const u32 B = sh_B;

  for (u32 i = tid; i < (u32)MT; i += 1024) {
    const u64 e = lb[i];
    if (e != 0 && binOf((u32)(e >> 32)) >= B) {
      const u32 p = atomicAdd(&sh_cc, 1u);
      if (p < 512) sel[p] = e;
    }
  }
  __syncthreads();
  u32 cc = sh_cc;

  if (cc > 512) {
    // pathological tie/bin density: exact radix fallback over nonzero entries
    auto bsum = [&](u32 v) -> u32 {
#pragma unroll
      for (int off = 32; off > 0; off >>= 1) v += __shfl_down(v, off, 64);
      if (lane == 0) wsum[wid] = v;
      __syncthreads();
      u32 t = 0;
#pragma unroll
      for (int wq = 0; wq < 16; ++wq) t += wsum[wq];
      __syncthreads();
      return t;
    };
    u64 T = 0;
#pragma unroll 1
    for (int bit = 47; bit >= 0; --bit) {
      if (isbf && bit >= 18 && bit < 34) continue;
      const u64 T2 = T | (1ull << bit);
      u32 cn = 0;
      for (u32 i = tid; i < (u32)MT; i += 1024) {
        const u64 e = lb[i];
        cn += (e != 0 && (e >> 14) >= T2) ? 1u : 0u;
      }
      if (bsum(cn) >= (u32)NK) T = T2;
    }
    __syncthreads();
    if (tid == 0) sh_cc = 0;
    __syncthreads();
    for (u32 i = tid; i < (u32)MT; i += 1024) {
      const u64 e = lb[i];
      if (e != 0 && (e >> 14) >= T) {
        const u32 p = atomicAdd(&sh_cc, 1u);
        if (p < 512) sel[p] = e;
      }
    }
    __syncthreads();
    cc = sh_cc;
  }

  for (u32 p = cc + tid; p < 512; p += 1024) sel[p] = 0;
  __syncthreads();

#pragma unroll 1
  for (u32 ks = 2; ks <= 512; ks <<= 1) {
#pragma unroll 1
    for (u32 j = ks >> 1; j > 0; j >>= 1) {
      if (tid < 512) {
        const u32 i = (u32)tid, ixj = i ^ j;
        if (ixj > i) {
          const u64 a = sel[i], c2 = sel[ixj];
          const bool up = ((i & ks) == 0);
          if (up ? (a > c2) : (a < c2)) { sel[i] = c2; sel[ixj] = a; }
        }
      }
      __syncthreads();
    }
  }

  if (tid < NK) emit_row(inv, isbf, b, tid, sel[511 - tid], outv);
}

extern "C" void kernel_launch(void* const* d_in, const int* in_sizes, int n_in,
                              void* d_out, int out_size, void* d_ws, size_t ws_size,
                              hipStream_t stream) {
  (void)in_sizes; (void)n_in; (void)out_size;
  const void* in = d_in[0];
  char* ws = (char*)d_ws;

  // layout: meta u32[8] @0 | hist u32[2*4096] @32 (32,768) | list u64[2*MT] @32,800
  //         (2,875,200) | keysT u32[2*NC*NA] @2,908,032 (41,843,744) => 44,751,776 total
  u32* meta  = (u32*)ws;
  u32* hist  = (u32*)(ws + 32);
  u64* list  = (u64*)(ws + 32800);
  u32* keysT = (u32*)(ws + 2908032);
  const bool tier1 = ws_size >= 44751776u;   // coalesced key transpose enabled

  hipLaunchKernelGGL(k_detect, dim3(1), dim3(256), 0, stream, (const u16*)in, meta, hist);
  if (tier1) {
    hipLaunchKernelGGL(k_transpose_keys, dim3(10, 137, 2), dim3(256), 0, stream,
                       in, meta, keysT);
  }
  hipLaunchKernelGGL(k_select_nms, dim3(NB * NC), dim3(256), 0, stream,
                     in, meta, list, hist, keysT, tier1 ? 1 : 0);
  hipLaunchKernelGGL(k_topk, dim3(NB), dim3(1024), 0, stream,
                     in, meta, list, hist, d_out);
}

// Round 7
// 316.466 us; speedup vs baseline: 6.1995x; 5.0974x over previous
//
#include <hip/hip_runtime.h>
#include <hip/hip_bf16.h>
#include <stdint.h>

typedef unsigned short u16;
typedef uint32_t u32;
typedef uint64_t u64;

#define NB 2
#define NA 8732
#define ND 604
#define NC 599
#define NM 300
#define NK 200
#define MT (NC * NM)     // 179700
#define NA4 (NA / 4)     // 2183
#define CONF 0.01f
#define NBIN 4096

// T preset: scores in (0.01,1) => f32 bits 31..26 are 001111 -> composite bits 45..40 = 01111
#define T_PRESET (0xFull << 40)

__device__ __forceinline__ float bf2f(u16 u) { return __uint_as_float(((u32)u) << 16); }

// global top-k bin: fine resolution near s=1 (kept scores concentrate in (0.966,1)).
// bin ASCENDS as score DESCENDS. Monotone; identical arithmetic at emit & collect.
__device__ __forceinline__ u32 binTop(u32 sbits) {
  const float t = __fsub_rn(1.0f, __uint_as_float(sbits));
  const float u = __fmul_rn(t, 65536.0f);
  u32 bin = (u32)u;
  return bin > (NBIN - 1) ? (NBIN - 1) : bin;
}

// per-class coarse score bin (ascending in score), for the 256-bin LDS histogram
__device__ __forceinline__ u32 bin8(u32 kbits) {
  u32 bin = (u32)__fmul_rn(__uint_as_float(kbits), 256.0f);
  return bin > 255 ? 255 : bin;
}

// meta[0] = input storage is true-bf16. Also zeroes the per-batch score histogram.
__global__ void k_detect(const u16* __restrict__ in, u32* __restrict__ meta,
                         u32* __restrict__ hist) {
  __shared__ u32 ws4[4], wz4[4];
  const int tid = threadIdx.x, lane = tid & 63, wid = tid >> 6;
  u32 ct = 0, cz = 0;
  for (int i = tid; i < 8192; i += 256) {
    const u16 v = in[i];
    ct += (u32)(v >> 15);
    cz += (u32)(((i & 1) == 0) && (v == 0));
  }
  for (int i = tid; i < NB * NBIN; i += 256) hist[i] = 0u;  // ws is 0xAA-poisoned
#pragma unroll
  for (int off = 32; off > 0; off >>= 1) {
    ct += __shfl_down(ct, off, 64);
    cz += __shfl_down(cz, off, 64);
  }
  if (lane == 0) { ws4[wid] = ct; wz4[wid] = cz; }
  __syncthreads();
  if (tid == 0) {
    const u32 tot_top = ws4[0] + ws4[1] + ws4[2] + ws4[3];
    const u32 tot_evz = wz4[0] + wz4[1] + wz4[2] + wz4[3];
    meta[0] = (tot_top == 0 && tot_evz < 1024) ? 1u : 0u;  // else f32 storage
    meta[1] = 0u; meta[2] = 0u; meta[3] = 0u;
  }
}

// tiled transpose of class scores -> thresholded u32 keys [b][c][n] (coalesced both sides)
__global__ __launch_bounds__(256) void k_transpose_keys(const void* __restrict__ inv,
                                                        const u32* __restrict__ meta,
                                                        u32* __restrict__ keysT) {
  __shared__ u32 tile[64][65];
  const u32 isbf = meta[0];
  const int c0 = blockIdx.x * 64, n0 = blockIdx.y * 64, b = blockIdx.z;
  const int tj = threadIdx.x & 63, t4 = threadIdx.x >> 6;
  const u16* inh = (const u16*)inv;
  const float* inf_ = (const float*)inv;
#pragma unroll
  for (int kk = 0; kk < 16; ++kk) {
    const int i = t4 + kk * 4;
    const int n = n0 + i, c = c0 + tj;
    u32 kx = 0;
    if (n < NA && c < NC) {
      const size_t idx = (size_t)(b * NA + n) * ND + 1 + c;
      const float f = isbf ? bf2f(inh[idx]) : inf_[idx];
      kx = (f > CONF) ? __float_as_uint(f) : 0u;
    }
    tile[i][tj] = kx;
  }
  __syncthreads();
#pragma unroll
  for (int kk = 0; kk < 16; ++kk) {
    const int j = t4 + kk * 4;
    const int c = c0 + j, n = n0 + tj;
    if (c < NC && n < NA) keysT[(size_t)(b * NC + c) * NA + n] = tile[tj][j];
  }
}

// per-(b,c): exact stable top-300 via LDS-histogram superset + full-composite sort
// (radix fallback only if superset > 512), then greedy NMS. Kept entries land at
// FIXED slots list[b*MT + c*NM + rank] (0 if not kept) -- coalesced, no global counter.
__global__ __launch_bounds__(256) void k_select_nms(const void* __restrict__ inv,
                                                    const u32* __restrict__ meta,
                                                    u64* __restrict__ list,
                                                    u32* __restrict__ hist,
                                                    const u32* __restrict__ keysT,
                                                    const int use_keys) {
  const int bc = blockIdx.x;
  const int b = bc / NC;
  const int c = bc - b * NC;
  const int tid = threadIdx.x;
  const int lane = tid & 63;
  const int wid = tid >> 6;

  __shared__ u32 wsum[4];
  __shared__ u64 cand[512];
  __shared__ u32 shist[256];
  __shared__ u32 sh_cnt, sh_B;

  const u32 isbf = meta[0];

  // key[e] = f32 bits of score if score > CONF else 0 (NaN -> 0).
  // composite = (key<<14) | (16383 - n): unique per anchor.
  u32 key[36];
  if (use_keys) {
    const uint4* col4 = (const uint4*)(keysT + (size_t)(b * NC + c) * NA);
#pragma unroll
    for (int r = 0; r < 9; ++r) {
      const int i4 = r * 256 + tid;
      if (i4 < NA4) {
        const uint4 k4 = col4[i4];
        key[r * 4 + 0] = k4.x; key[r * 4 + 1] = k4.y;
        key[r * 4 + 2] = k4.z; key[r * 4 + 3] = k4.w;
      } else {
        key[r * 4 + 0] = 0; key[r * 4 + 1] = 0; key[r * 4 + 2] = 0; key[r * 4 + 3] = 0;
      }
    }
  } else if (isbf) {
    const u16* basep = (const u16*)inv + (size_t)b * NA * ND + 1 + c;
#pragma unroll
    for (int r = 0; r < 9; ++r) {
      const int i4 = r * 256 + tid;
#pragma unroll
      for (int kk = 0; kk < 4; ++kk) {
        u32 kx = 0;
        if (i4 < NA4) {
          const float f = bf2f(basep[(size_t)(i4 * 4 + kk) * ND]);
          kx = (f > CONF) ? __float_as_uint(f) : 0u;
        }
        key[r * 4 + kk] = kx;
      }
    }
  } else {
    const float* basep = (const float*)inv + (size_t)b * NA * ND + 1 + c;
#pragma unroll
    for (int r = 0; r < 9; ++r) {
      const int i4 = r * 256 + tid;
#pragma unroll
      for (int kk = 0; kk < 4; ++kk) {
        u32 kx = 0;
        if (i4 < NA4) {
          const float f = basep[(size_t)(i4 * 4 + kk) * ND];
          kx = (f > CONF) ? __float_as_uint(f) : 0u;
        }
        key[r * 4 + kk] = kx;
      }
    }
  }

  // --- LDS histogram over coarse score bins; threshold bin B with cum >= 300 ---
  shist[tid] = 0;
  if (tid == 0) { sh_cnt = 0; sh_B = 0; }
  cand[tid] = 0; cand[tid + 256] = 0;
  __syncthreads();
#pragma unroll
  for (int e = 0; e < 36; ++e) atomicAdd(&shist[bin8(key[e])], 1u);
  __syncthreads();
  if (tid == 0) {
    u32 acc = 0, B = 0;
    for (int t = 255; t >= 0; --t) {
      acc += shist[t];
      if (acc >= (u32)NM) { B = (u32)t; break; }
    }
    sh_B = B;   // if cum never reaches 300, B=0 -> collect-all -> radix fallback
  }
  __syncthreads();
  const u32 B = sh_B;

  // collect superset (all entries with score-bin >= B); contains every top-300 composite
  // since score dominates the composite ordering.
#pragma unroll
  for (int r = 0; r < 9; ++r) {
#pragma unroll
    for (int kk = 0; kk < 4; ++kk) {
      const u32 k = key[r * 4 + kk];
      if (bin8(k) >= B) {
        const u32 nn = 16383u - (u32)((r * 256 + tid) * 4 + kk);
        const u32 p = atomicAdd(&sh_cnt, 1u);
        if (p < 512) cand[p] = (((u64)k) << 14) | (u64)nn;
      }
    }
  }
  __syncthreads();

  if (sh_cnt > 512) {
    // fallback: exact 40-bit radix for the 300th composite, then exact collect
    auto blockSum = [&](u32 v) -> u32 {
#pragma unroll
      for (int off = 32; off > 0; off >>= 1) v += __shfl_down(v, off, 64);
      if (lane == 0) wsum[wid] = v;
      __syncthreads();
      const u32 tot = wsum[0] + wsum[1] + wsum[2] + wsum[3];
      __syncthreads();
      return tot;
    };
    u64 T = T_PRESET;
#pragma unroll 1
    for (int bit = 39; bit >= 0; --bit) {
      if (isbf && bit >= 14 && bit < 30) continue;
      const u64 T2 = T | (1ull << bit);
      const u32 Thi = (u32)(T2 >> 14);
      const u32 Tlo = (u32)(T2 & 0x3FFFu);
      u32 cnt = 0;
#pragma unroll
      for (int r = 0; r < 9; ++r) {
#pragma unroll
        for (int kk = 0; kk < 4; ++kk) {
          const u32 k = key[r * 4 + kk];
          const u32 nn = 16383u - (u32)((r * 256 + tid) * 4 + kk);
          cnt += (k > Thi || (k == Thi && nn >= Tlo)) ? 1u : 0u;
        }
      }
      if (blockSum(cnt) >= NM) T = T2;
    }
    if (tid == 0) sh_cnt = 0;
    cand[tid] = 0; cand[tid + 256] = 0;
    __syncthreads();
    const u32 Thi = (u32)(T >> 14);
    const u32 Tlo = (u32)(T & 0x3FFFu);
#pragma unroll
    for (int r = 0; r < 9; ++r) {
#pragma unroll
      for (int kk = 0; kk < 4; ++kk) {
        const u32 k = key[r * 4 + kk];
        const u32 nn = 16383u - (u32)((r * 256 + tid) * 4 + kk);
        if (k > Thi || (k == Thi && nn >= Tlo)) {
          const u32 p = atomicAdd(&sh_cnt, 1u);
          if (p < 512) cand[p] = (((u64)k) << 14) | (u64)nn;
        }
      }
    }
    __syncthreads();
  }

  // bitonic ascending sort of cand[512]; top-300 composites end at 511..212
#pragma unroll 1
  for (u32 ks = 2; ks <= 512; ks <<= 1) {
#pragma unroll 1
    for (u32 j = ks >> 1; j > 0; j >>= 1) {
#pragma unroll
      for (int rep = 0; rep < 2; ++rep) {
        const u32 i = tid + rep * 256;
        const u32 ixj = i ^ j;
        if (ixj > i) {
          const u64 a = cand[i], bb = cand[ixj];
          const bool up = ((i & ks) == 0);
          if (up ? (a > bb) : (a < bb)) { cand[i] = bb; cand[ixj] = a; }
        }
      }
      __syncthreads();
    }
  }

  // wave 0: greedy NMS over the top-300 (registers + shuffles). _rn intrinsics
  // prevent FMA contraction diverging from the reference's rounded arithmetic.
  if (tid < 64) {
    float by0[5], bx0[5], by1[5], bx1[5], bar[5], bv[5];
    u32 bn[5];
    bool sup[5], keep[5];
#pragma unroll
    for (int q = 0; q < 5; ++q) {
      const int j = q * 64 + lane;
      keep[q] = false;
      by0[q] = bx0[q] = by1[q] = bx1[q] = bar[q] = 0.f;
      if (j < NM) {
        const u64 e = cand[511 - j];
        const u32 sb = (u32)(e >> 14);
        u32 n = 16383u - ((u32)e & 0x3FFFu);
        if (n >= (u32)NA) n = 0;      // zero-pad slot
        sup[q] = false;
        bn[q] = n;
        bv[q] = __uint_as_float(sb);  // 0.0f for pad/below-conf
        float cx, cy, w, h;
        if (isbf) {
          const u16* bp = (const u16*)inv + (size_t)(b * NA + n) * ND + 600;
          const ushort4 ub = *(const ushort4*)bp;
          cx = bf2f(ub.x); cy = bf2f(ub.y); w = bf2f(ub.z); h = bf2f(ub.w);
        } else {
          const float* bp = (const float*)inv + (size_t)(b * NA + n) * ND + 600;
          const float4 f4 = *(const float4*)bp;
          cx = f4.x; cy = f4.y; w = f4.z; h = f4.w;
        }
        const float y0 = __fsub_rn(cy, __fmul_rn(h, 0.5f));
        const float x0 = __fsub_rn(cx, __fmul_rn(w, 0.5f));
        const float y1 = __fadd_rn(cy, __fmul_rn(h, 0.5f));
        const float x1 = __fadd_rn(cx, __fmul_rn(w, 0.5f));
        by0[q] = y0; bx0[q] = x0; by1[q] = y1; bx1[q] = x1;
        bar[q] = __fmul_rn(__fsub_rn(y1, y0), __fsub_rn(x1, x0));
      } else {
        bv[q] = 0.f; bn[q] = 0; sup[q] = true;
      }
    }
#pragma unroll
    for (int qi = 0; qi < 5; ++qi) {
      const int lim = (qi == 4) ? (NM - 256) : 64;
#pragma unroll 1
      for (int li = 0; li < lim; ++li) {
        const int kq = (!sup[qi] && bv[qi] > CONF) ? 1 : 0;
        const int ki = __shfl(kq, li, 64);
        if (lane == li) keep[qi] = (ki != 0);
        if (ki) {
          const float iy0 = __shfl(by0[qi], li, 64);
          const float ix0 = __shfl(bx0[qi], li, 64);
          const float iy1 = __shfl(by1[qi], li, 64);
          const float ix1 = __shfl(bx1[qi], li, 64);
          const float iar = __shfl(bar[qi], li, 64);
          const int i = qi * 64 + li;
#pragma unroll
          for (int q = 0; q < 5; ++q) {
            const int j = q * 64 + lane;
            if (j > i && j < NM && !sup[q]) {
              const float ih = fmaxf(__fsub_rn(fminf(iy1, by1[q]), fmaxf(iy0, by0[q])), 0.f);
              const float iw = fmaxf(__fsub_rn(fminf(ix1, bx1[q]), fmaxf(ix0, bx0[q])), 0.f);
              const float inter = __fmul_rn(ih, iw);
              const float uni = __fsub_rn(__fadd_rn(iar, bar[q]), inter);
              if (uni > 0.f && __fdiv_rn(inter, uni) > 0.45f) sup[q] = true;
            }
          }
        }
      }
    }
    // fixed-slot emission: coalesced, no global counter; scattered hist atomics
#pragma unroll
    for (int q = 0; q < 5; ++q) {
      const int j = q * 64 + lane;
      if (j < NM) {
        u64 entry = 0;
        if (keep[q]) {
          const u32 sb = __float_as_uint(bv[q]);
          const u32 flat = (u32)c * NM + (u32)j;
          entry = (((u64)sb) << 32) | (((u64)(0x3FFFFu - flat)) << 14) | (u64)bn[q];
          atomicAdd(&hist[(size_t)b * NBIN + binTop(sb)], 1u);
        }
        list[(size_t)b * MT + (u32)c * NM + (u32)j] = entry;
      }
    }
  }
}

// shared epilogue: corner->center transform + dtype-matched store
__device__ __forceinline__ void emit_row(const void* inv, u32 isbf, int b, int tid,
                                         u64 e, void* outv) {
  float o0 = 0, o1 = 0, o2 = 0, o3 = 0, o4 = 0, o5 = 0;
  if (e != 0) {
    const u32 sb = (u32)(e >> 32);
    const u32 flat = 0x3FFFFu - ((u32)(e >> 14) & 0x3FFFFu);
    const u32 anchor = (u32)e & 0x3FFFu;
    const u32 cls = flat / NM;
    float cx, cy, w, h;
    if (isbf) {
      const u16* bp = (const u16*)inv + (size_t)(b * NA + anchor) * ND + 600;
      const ushort4 ub = *(const ushort4*)bp;
      cx = bf2f(ub.x); cy = bf2f(ub.y); w = bf2f(ub.z); h = bf2f(ub.w);
    } else {
      const float* bp = (const float*)inv + (size_t)(b * NA + anchor) * ND + 600;
      const float4 f4 = *(const float4*)bp;
      cx = f4.x; cy = f4.y; w = f4.z; h = f4.w;
    }
    const float y0 = __fsub_rn(cy, __fmul_rn(h, 0.5f));
    const float x0 = __fsub_rn(cx, __fmul_rn(w, 0.5f));
    const float y1 = __fadd_rn(cy, __fmul_rn(h, 0.5f));
    const float x1 = __fadd_rn(cx, __fmul_rn(w, 0.5f));
    const float th = __fsub_rn(y1, y0), tw = __fsub_rn(x1, x0);
    o0 = (float)(cls + 1);
    o1 = __uint_as_float(sb);
    o2 = __fadd_rn(x0, __fmul_rn(tw, 0.5f));
    o3 = __fadd_rn(y0, __fmul_rn(th, 0.5f));
    o4 = tw;
    o5 = th;
  }
  if (isbf) {
    __hip_bfloat16* op = (__hip_bfloat16*)outv + ((size_t)b * NK + tid) * 6;
    op[0] = __float2bfloat16(o0); op[1] = __float2bfloat16(o1);
    op[2] = __float2bfloat16(o2); op[3] = __float2bfloat16(o3);
    op[4] = __float2bfloat16(o4); op[5] = __float2bfloat16(o5);
  } else {
    float* op = (float*)outv + ((size_t)b * NK + tid) * 6;
    op[0] = o0; op[1] = o1; op[2] = o2; op[3] = o3; op[4] = o4; op[5] = o5;
  }
}

// per batch: histogram-guided exact top-200 over the fixed-slot list.
__global__ __launch_bounds__(1024) void k_topk(const void* __restrict__ inv,
                                               const u32* __restrict__ meta,
                                               const u64* __restrict__ list,
                                               const u32* __restrict__ hist,
                                               void* __restrict__ outv) {
  const int b = blockIdx.x, tid = threadIdx.x, lane = tid & 63, wid = tid >> 6;
  const u32 isbf = meta[0];
  const u64* lb = list + (size_t)b * MT;
  const u32* hh = hist + (size_t)b * NBIN;

  __shared__ u32 ps[1024];
  __shared__ u64 sel[512];
  __shared__ u32 wsum[16];
  __shared__ u32 sh_B, sh_cc;

  {
    const uint4 hv = ((const uint4*)hh)[tid];
    ps[tid] = hv.x + hv.y + hv.z + hv.w;
  }
  if (tid == 0) { sh_cc = 0; sh_B = NBIN - 1; }
  __syncthreads();
  if (tid == 0) {
    u32 acc = 0;
    // bins ascend as score descends: scan from bin 0 (highest scores)
    for (int t = 0; t < 1024; ++t) {
      if (acc + ps[t] >= (u32)NK) {
        u32 a2 = acc, B = (u32)(NBIN - 1);
        for (int jj = 0; jj < 4; ++jj) {
          const u32 cb = hh[t * 4 + jj];
          if (a2 + cb >= (u32)NK) { B = (u32)(t * 4 + jj); break; }
          a2 += cb;
        }
        sh_B = B;
        break;
      }
      acc += ps[t];
    }
    // never reached 200 => sh_B stays NBIN-1 => collect everything
  }
  __syncthreads();
  const u32 B = sh_B;

  for (u32 i = tid; i < (u32)MT; i += 1024) {
    const u64 e = lb[i];
    if (e != 0 && binTop((u32)(e >> 32)) <= B) {
      const u32 p = atomicAdd(&sh_cc, 1u);
      if (p < 512) sel[p] = e;
    }
  }
  __syncthreads();
  u32 cc = sh_cc;

  if (cc > 512) {
    // pathological density: exact radix fallback over nonzero entries
    auto bsum = [&](u32 v) -> u32 {
#pragma unroll
      for (int off = 32; off > 0; off >>= 1) v += __shfl_down(v, off, 64);
      if (lane == 0) wsum[wid] = v;
      __syncthreads();
      u32 t = 0;
#pragma unroll
      for (int wq = 0; wq < 16; ++wq) t += wsum[wq];
      __syncthreads();
      return t;
    };
    u64 T = 0;
#pragma unroll 1
    for (int bit = 47; bit >= 0; --bit) {
      if (isbf && bit >= 18 && bit < 34) continue;
      const u64 T2 = T | (1ull << bit);
      u32 cn = 0;
      for (u32 i = tid; i < (u32)MT; i += 1024) {
        const u64 e = lb[i];
        cn += (e != 0 && (e >> 14) >= T2) ? 1u : 0u;
      }
      if (bsum(cn) >= (u32)NK) T = T2;
    }
    __syncthreads();
    if (tid == 0) sh_cc = 0;
    __syncthreads();
    for (u32 i = tid; i < (u32)MT; i += 1024) {
      const u64 e = lb[i];
      if (e != 0 && (e >> 14) >= T) {
        const u32 p = atomicAdd(&sh_cc, 1u);
        if (p < 512) sel[p] = e;
      }
    }
    __syncthreads();
    cc = sh_cc;
  }

  for (u32 p = cc + tid; p < 512; p += 1024) sel[p] = 0;
  __syncthreads();

#pragma unroll 1
  for (u32 ks = 2; ks <= 512; ks <<= 1) {
#pragma unroll 1
    for (u32 j = ks >> 1; j > 0; j >>= 1) {
      if (tid < 512) {
        const u32 i = (u32)tid, ixj = i ^ j;
        if (ixj > i) {
          const u64 a = sel[i], c2 = sel[ixj];
          const bool up = ((i & ks) == 0);
          if (up ? (a > c2) : (a < c2)) { sel[i] = c2; sel[ixj] = a; }
        }
      }
      __syncthreads();
    }
  }

  if (tid < NK) emit_row(inv, isbf, b, tid, sel[511 - tid], outv);
}

extern "C" void kernel_launch(void* const* d_in, const int* in_sizes, int n_in,
                              void* d_out, int out_size, void* d_ws, size_t ws_size,
                              hipStream_t stream) {
  (void)in_sizes; (void)n_in; (void)out_size;
  const void* in = d_in[0];
  char* ws = (char*)d_ws;

  // layout: meta u32[8] @0 | hist u32[2*4096] @32 (32,768) | list u64[2*MT] @32,800
  //         (2,875,200) | keysT u32[2*NC*NA] @2,908,032 (41,843,744) => 44,751,776 total
  u32* meta  = (u32*)ws;
  u32* hist  = (u32*)(ws + 32);
  u64* list  = (u64*)(ws + 32800);
  u32* keysT = (u32*)(ws + 2908032);
  const bool tier1 = ws_size >= 44751776u;   // coalesced key transpose enabled

  hipLaunchKernelGGL(k_detect, dim3(1), dim3(256), 0, stream, (const u16*)in, meta, hist);
  if (tier1) {
    hipLaunchKernelGGL(k_transpose_keys, dim3(10, 137, 2), dim3(256), 0, stream,
                       in, meta, keysT);
  }
  hipLaunchKernelGGL(k_select_nms, dim3(NB * NC), dim3(256), 0, stream,
                     in, meta, list, hist, keysT, tier1 ? 1 : 0);
  hipLaunchKernelGGL(k_topk, dim3(NB), dim3(1024), 0, stream,
                     in, meta, list, hist, d_out);
}

// Round 8
// 275.853 us; speedup vs baseline: 7.1122x; 1.1472x over previous
//
#include <hip/hip_runtime.h>
#include <hip/hip_bf16.h>
#include <stdint.h>

typedef unsigned short u16;
typedef uint32_t u32;
typedef uint64_t u64;

#define NB 2
#define NA 8732
#define ND 604
#define NC 599
#define NM 300
#define NK 200
#define MT (NC * NM)     // 179700
#define NA4 (NA / 4)     // 2183
#define CONF 0.01f
#define NBIN 4096

#define T_PRESET (0xFull << 40)

__device__ __forceinline__ float bf2f(u16 u) { return __uint_as_float(((u32)u) << 16); }

// global top-k bin: fine resolution near s=1 (kept scores concentrate in (0.966,1)).
// bin ASCENDS as score DESCENDS.
__device__ __forceinline__ u32 binTop(u32 sbits) {
  const float t = __fsub_rn(1.0f, __uint_as_float(sbits));
  const float u = __fmul_rn(t, 65536.0f);
  u32 bin = (u32)u;
  return bin > (NBIN - 1) ? (NBIN - 1) : bin;
}

// per-class coarse score bin (ascending in score)
__device__ __forceinline__ u32 bin8(u32 kbits) {
  u32 bin = (u32)__fmul_rn(__uint_as_float(kbits), 256.0f);
  return bin > 255 ? 255 : bin;
}

// meta[0] = input storage is true-bf16. Also zeroes the per-batch score histogram.
__global__ void k_detect(const u16* __restrict__ in, u32* __restrict__ meta,
                         u32* __restrict__ hist) {
  __shared__ u32 ws4[4], wz4[4];
  const int tid = threadIdx.x, lane = tid & 63, wid = tid >> 6;
  u32 ct = 0, cz = 0;
  for (int i = tid; i < 8192; i += 256) {
    const u16 v = in[i];
    ct += (u32)(v >> 15);
    cz += (u32)(((i & 1) == 0) && (v == 0));
  }
  for (int i = tid; i < NB * NBIN; i += 256) hist[i] = 0u;
#pragma unroll
  for (int off = 32; off > 0; off >>= 1) {
    ct += __shfl_down(ct, off, 64);
    cz += __shfl_down(cz, off, 64);
  }
  if (lane == 0) { ws4[wid] = ct; wz4[wid] = cz; }
  __syncthreads();
  if (tid == 0) {
    const u32 tot_top = ws4[0] + ws4[1] + ws4[2] + ws4[3];
    const u32 tot_evz = wz4[0] + wz4[1] + wz4[2] + wz4[3];
    meta[0] = (tot_top == 0 && tot_evz < 1024) ? 1u : 0u;  // else f32 storage
    meta[1] = 0u; meta[2] = 0u; meta[3] = 0u;
  }
}

// tiled transpose of class scores -> thresholded u32 keys [b][c][n]
__global__ __launch_bounds__(256) void k_transpose_keys(const void* __restrict__ inv,
                                                        const u32* __restrict__ meta,
                                                        u32* __restrict__ keysT) {
  __shared__ u32 tile[64][65];
  const u32 isbf = meta[0];
  const int c0 = blockIdx.x * 64, n0 = blockIdx.y * 64, b = blockIdx.z;
  const int tj = threadIdx.x & 63, t4 = threadIdx.x >> 6;
  const u16* inh = (const u16*)inv;
  const float* inf_ = (const float*)inv;
#pragma unroll
  for (int kk = 0; kk < 16; ++kk) {
    const int i = t4 + kk * 4;
    const int n = n0 + i, c = c0 + tj;
    u32 kx = 0;
    if (n < NA && c < NC) {
      const size_t idx = (size_t)(b * NA + n) * ND + 1 + c;
      const float f = isbf ? bf2f(inh[idx]) : inf_[idx];
      kx = (f > CONF) ? __float_as_uint(f) : 0u;
    }
    tile[i][tj] = kx;
  }
  __syncthreads();
#pragma unroll
  for (int kk = 0; kk < 16; ++kk) {
    const int j = t4 + kk * 4;
    const int c = c0 + j, n = n0 + tj;
    if (c < NC && n < NA) keysT[(size_t)(b * NC + c) * NA + n] = tile[tj][j];
  }
}

// per-(b,c): exact stable top-300 via LDS-histogram superset + full-composite bitonic
// sort (radix fallback only if superset > 512). Writes the 300 sorted (descending)
// composites ((key<<14)|(16383-n)) to candws[bc*300 + rank]. NO NMS here.
__global__ __launch_bounds__(256) void k_select(const void* __restrict__ inv,
                                                const u32* __restrict__ meta,
                                                u64* __restrict__ candws,
                                                const u32* __restrict__ keysT,
                                                const int use_keys) {
  const int bc = blockIdx.x;
  const int b = bc / NC;
  const int c = bc - b * NC;
  const int tid = threadIdx.x;
  const int lane = tid & 63;
  const int wid = tid >> 6;

  __shared__ u32 wsum[4];
  __shared__ u64 cand[512];
  __shared__ u32 shist[256];
  __shared__ u32 sh_cnt, sh_B;

  const u32 isbf = meta[0];

  u32 key[36];
  if (use_keys) {
    const uint4* col4 = (const uint4*)(keysT + (size_t)(b * NC + c) * NA);
#pragma unroll
    for (int r = 0; r < 9; ++r) {
      const int i4 = r * 256 + tid;
      if (i4 < NA4) {
        const uint4 k4 = col4[i4];
        key[r * 4 + 0] = k4.x; key[r * 4 + 1] = k4.y;
        key[r * 4 + 2] = k4.z; key[r * 4 + 3] = k4.w;
      } else {
        key[r * 4 + 0] = 0; key[r * 4 + 1] = 0; key[r * 4 + 2] = 0; key[r * 4 + 3] = 0;
      }
    }
  } else if (isbf) {
    const u16* basep = (const u16*)inv + (size_t)b * NA * ND + 1 + c;
#pragma unroll
    for (int r = 0; r < 9; ++r) {
      const int i4 = r * 256 + tid;
#pragma unroll
      for (int kk = 0; kk < 4; ++kk) {
        u32 kx = 0;
        if (i4 < NA4) {
          const float f = bf2f(basep[(size_t)(i4 * 4 + kk) * ND]);
          kx = (f > CONF) ? __float_as_uint(f) : 0u;
        }
        key[r * 4 + kk] = kx;
      }
    }
  } else {
    const float* basep = (const float*)inv + (size_t)b * NA * ND + 1 + c;
#pragma unroll
    for (int r = 0; r < 9; ++r) {
      const int i4 = r * 256 + tid;
#pragma unroll
      for (int kk = 0; kk < 4; ++kk) {
        u32 kx = 0;
        if (i4 < NA4) {
          const float f = basep[(size_t)(i4 * 4 + kk) * ND];
          kx = (f > CONF) ? __float_as_uint(f) : 0u;
        }
        key[r * 4 + kk] = kx;
      }
    }
  }

  // LDS histogram over coarse score bins; threshold bin B with cum >= 300
  shist[tid] = 0;
  if (tid == 0) { sh_cnt = 0; sh_B = 0; }
  cand[tid] = 0; cand[tid + 256] = 0;
  __syncthreads();
#pragma unroll
  for (int e = 0; e < 36; ++e) atomicAdd(&shist[bin8(key[e])], 1u);
  __syncthreads();
  if (tid == 0) {
    u32 acc = 0, B = 0;
    for (int t = 255; t >= 0; --t) {
      acc += shist[t];
      if (acc >= (u32)NM) { B = (u32)t; break; }
    }
    sh_B = B;
  }
  __syncthreads();
  const u32 B = sh_B;

  // superset collect (score dominates composite ordering => contains all top-300)
#pragma unroll
  for (int r = 0; r < 9; ++r) {
#pragma unroll
    for (int kk = 0; kk < 4; ++kk) {
      const u32 k = key[r * 4 + kk];
      if (bin8(k) >= B) {
        const u32 nn = 16383u - (u32)((r * 256 + tid) * 4 + kk);
        const u32 p = atomicAdd(&sh_cnt, 1u);
        if (p < 512) cand[p] = (((u64)k) << 14) | (u64)nn;
      }
    }
  }
  __syncthreads();

  if (sh_cnt > 512) {
    // fallback: exact radix for the 300th composite, then exact collect
    auto blockSum = [&](u32 v) -> u32 {
#pragma unroll
      for (int off = 32; off > 0; off >>= 1) v += __shfl_down(v, off, 64);
      if (lane == 0) wsum[wid] = v;
      __syncthreads();
      const u32 tot = wsum[0] + wsum[1] + wsum[2] + wsum[3];
      __syncthreads();
      return tot;
    };
    u64 T = T_PRESET;
#pragma unroll 1
    for (int bit = 39; bit >= 0; --bit) {
      if (isbf && bit >= 14 && bit < 30) continue;
      const u64 T2 = T | (1ull << bit);
      const u32 Thi = (u32)(T2 >> 14);
      const u32 Tlo = (u32)(T2 & 0x3FFFu);
      u32 cnt = 0;
#pragma unroll
      for (int r = 0; r < 9; ++r) {
#pragma unroll
        for (int kk = 0; kk < 4; ++kk) {
          const u32 k = key[r * 4 + kk];
          const u32 nn = 16383u - (u32)((r * 256 + tid) * 4 + kk);
          cnt += (k > Thi || (k == Thi && nn >= Tlo)) ? 1u : 0u;
        }
      }
      if (blockSum(cnt) >= NM) T = T2;
    }
    if (tid == 0) sh_cnt = 0;
    cand[tid] = 0; cand[tid + 256] = 0;
    __syncthreads();
    const u32 Thi = (u32)(T >> 14);
    const u32 Tlo = (u32)(T & 0x3FFFu);
#pragma unroll
    for (int r = 0; r < 9; ++r) {
#pragma unroll
      for (int kk = 0; kk < 4; ++kk) {
        const u32 k = key[r * 4 + kk];
        const u32 nn = 16383u - (u32)((r * 256 + tid) * 4 + kk);
        if (k > Thi || (k == Thi && nn >= Tlo)) {
          const u32 p = atomicAdd(&sh_cnt, 1u);
          if (p < 512) cand[p] = (((u64)k) << 14) | (u64)nn;
        }
      }
    }
    __syncthreads();
  }

  // bitonic ascending sort; top-300 land at 511..212
#pragma unroll 1
  for (u32 ks = 2; ks <= 512; ks <<= 1) {
#pragma unroll 1
    for (u32 j = ks >> 1; j > 0; j >>= 1) {
#pragma unroll
      for (int rep = 0; rep < 2; ++rep) {
        const u32 i = tid + rep * 256;
        const u32 ixj = i ^ j;
        if (ixj > i) {
          const u64 a = cand[i], bb = cand[ixj];
          const bool up = ((i & ks) == 0);
          if (up ? (a > bb) : (a < bb)) { cand[i] = bb; cand[ixj] = a; }
        }
      }
      __syncthreads();
    }
  }

  // write descending top-300 composites
  u64* cw = candws + (size_t)bc * NM;
  if (tid < NM) cw[tid] = cand[511 - tid];
  if (tid < NM - 256) cw[256 + tid] = cand[511 - 256 - tid];
}

// one wave per (b,c): greedy NMS over the 300 sorted candidates; in-place write-back
// of kept entries in final format (score32<<32 | (~flat18)<<14 | anchor14), 0 otherwise.
__global__ __launch_bounds__(64, 6) void k_nms(const void* __restrict__ inv,
                                               const u32* __restrict__ meta,
                                               u64* __restrict__ candws,
                                               u32* __restrict__ hist) {
  const int bc = blockIdx.x;
  const int b = bc / NC;
  const int c = bc - b * NC;
  const int lane = threadIdx.x;
  const u32 isbf = meta[0];
  u64* cw = candws + (size_t)bc * NM;

  float by0[5], bx0[5], by1[5], bx1[5], bar[5], bv[5];
  u32 bn[5];
  bool sup[5], keep[5];
#pragma unroll
  for (int q = 0; q < 5; ++q) {
    const int j = q * 64 + lane;
    keep[q] = false;
    by0[q] = bx0[q] = by1[q] = bx1[q] = bar[q] = 0.f;
    if (j < NM) {
      const u64 e = cw[j];
      const u32 sb = (u32)(e >> 14);
      u32 n = 16383u - ((u32)e & 0x3FFFu);
      if (n >= (u32)NA) n = 0;      // zero-pad slot
      sup[q] = false;
      bn[q] = n;
      bv[q] = __uint_as_float(sb);  // 0.0f for pad/below-conf
      float cx, cy, w, h;
      if (isbf) {
        const u16* bp = (const u16*)inv + (size_t)(b * NA + n) * ND + 600;
        const ushort4 ub = *(const ushort4*)bp;
        cx = bf2f(ub.x); cy = bf2f(ub.y); w = bf2f(ub.z); h = bf2f(ub.w);
      } else {
        const float* bp = (const float*)inv + (size_t)(b * NA + n) * ND + 600;
        const float4 f4 = *(const float4*)bp;
        cx = f4.x; cy = f4.y; w = f4.z; h = f4.w;
      }
      const float y0 = __fsub_rn(cy, __fmul_rn(h, 0.5f));
      const float x0 = __fsub_rn(cx, __fmul_rn(w, 0.5f));
      const float y1 = __fadd_rn(cy, __fmul_rn(h, 0.5f));
      const float x1 = __fadd_rn(cx, __fmul_rn(w, 0.5f));
      by0[q] = y0; bx0[q] = x0; by1[q] = y1; bx1[q] = x1;
      bar[q] = __fmul_rn(__fsub_rn(y1, y0), __fsub_rn(x1, x0));
    } else {
      bv[q] = 0.f; bn[q] = 0; sup[q] = true;
    }
  }
#pragma unroll
  for (int qi = 0; qi < 5; ++qi) {
    const int lim = (qi == 4) ? (NM - 256) : 64;
#pragma unroll 1
    for (int li = 0; li < lim; ++li) {
      const int kq = (!sup[qi] && bv[qi] > CONF) ? 1 : 0;
      const int ki = __shfl(kq, li, 64);
      if (lane == li) keep[qi] = (ki != 0);
      if (ki) {
        const float iy0 = __shfl(by0[qi], li, 64);
        const float ix0 = __shfl(bx0[qi], li, 64);
        const float iy1 = __shfl(by1[qi], li, 64);
        const float ix1 = __shfl(bx1[qi], li, 64);
        const float iar = __shfl(bar[qi], li, 64);
        const int i = qi * 64 + li;
#pragma unroll
        for (int q = 0; q < 5; ++q) {
          const int j = q * 64 + lane;
          if (j > i && j < NM && !sup[q]) {
            const float ih = fmaxf(__fsub_rn(fminf(iy1, by1[q]), fmaxf(iy0, by0[q])), 0.f);
            const float iw = fmaxf(__fsub_rn(fminf(ix1, bx1[q]), fmaxf(ix0, bx0[q])), 0.f);
            const float inter = __fmul_rn(ih, iw);
            const float uni = __fsub_rn(__fadd_rn(iar, bar[q]), inter);
            if (uni > 0.f && __fdiv_rn(inter, uni) > 0.45f) sup[q] = true;
          }
        }
      }
    }
  }
  // in-place write-back (block owns its slice; reads happened above)
#pragma unroll
  for (int q = 0; q < 5; ++q) {
    const int j = q * 64 + lane;
    if (j < NM) {
      u64 entry = 0;
      if (keep[q]) {
        const u32 sb = __float_as_uint(bv[q]);
        const u32 flat = (u32)c * NM + (u32)j;
        entry = (((u64)sb) << 32) | (((u64)(0x3FFFFu - flat)) << 14) | (u64)bn[q];
        atomicAdd(&hist[(size_t)b * NBIN + binTop(sb)], 1u);
      }
      cw[j] = entry;
    }
  }
}

// compute per-batch bin threshold B (cum >= 200 scanning from highest scores);
// also zero the collect counters (safe here: keysT is dead after k_select).
__global__ __launch_bounds__(1024) void k_thresh(const u32* __restrict__ hist,
                                                 u32* __restrict__ meta,
                                                 u32* __restrict__ selcnt) {
  __shared__ u32 ps[1024];
  const int tid = threadIdx.x;
  if (tid < NB) selcnt[tid] = 0;
  for (int b = 0; b < NB; ++b) {
    const u32* hh = hist + (size_t)b * NBIN;
    const uint4 hv = ((const uint4*)hh)[tid];
    ps[tid] = hv.x + hv.y + hv.z + hv.w;
    __syncthreads();
    if (tid == 0) {
      u32 acc = 0, B = (u32)(NBIN - 1);
      for (int t = 0; t < 1024; ++t) {
        if (acc + ps[t] >= (u32)NK) {
          u32 a2 = acc;
          for (int jj = 0; jj < 4; ++jj) {
            const u32 cb = hh[t * 4 + jj];
            if (a2 + cb >= (u32)NK) { B = (u32)(t * 4 + jj); break; }
            a2 += cb;
          }
          break;
        }
        acc += ps[t];
      }
      meta[4 + b] = B;   // never reached 200 => NBIN-1 => collect everything
    }
    __syncthreads();
  }
}

// full-chip scan of the kept list; append qualifying entries (~250/batch)
__global__ __launch_bounds__(256) void k_collect(const u64* __restrict__ list,
                                                 const u32* __restrict__ meta,
                                                 u32* __restrict__ selcnt,
                                                 u64* __restrict__ selbuf) {
  const u32 i = blockIdx.x * 256 + threadIdx.x;
  if (i >= (u32)(NB * MT)) return;
  const u32 b = (i < (u32)MT) ? 0u : 1u;
  const u64 e = list[i];
  if (e != 0 && binTop((u32)(e >> 32)) <= meta[4 + b]) {
    const u32 p = atomicAdd(&selcnt[b], 1u);
    if (p < 512) selbuf[(size_t)b * 512 + p] = e;
  }
}

// shared epilogue: corner->center transform + dtype-matched store
__device__ __forceinline__ void emit_row(const void* inv, u32 isbf, int b, int tid,
                                         u64 e, void* outv) {
  float o0 = 0, o1 = 0, o2 = 0, o3 = 0, o4 = 0, o5 = 0;
  if (e != 0) {
    const u32 sb = (u32)(e >> 32);
    const u32 flat = 0x3FFFFu - ((u32)(e >> 14) & 0x3FFFFu);
    const u32 anchor = (u32)e & 0x3FFFu;
    const u32 cls = flat / NM;
    float cx, cy, w, h;
    if (isbf) {
      const u16* bp = (const u16*)inv + (size_t)(b * NA + anchor) * ND + 600;
      const ushort4 ub = *(const ushort4*)bp;
      cx = bf2f(ub.x); cy = bf2f(ub.y); w = bf2f(ub.z); h = bf2f(ub.w);
    } else {
      const float* bp = (const float*)inv + (size_t)(b * NA + anchor) * ND + 600;
      const float4 f4 = *(const float4*)bp;
      cx = f4.x; cy = f4.y; w = f4.z; h = f4.w;
    }
    const float y0 = __fsub_rn(cy, __fmul_rn(h, 0.5f));
    const float x0 = __fsub_rn(cx, __fmul_rn(w, 0.5f));
    const float y1 = __fadd_rn(cy, __fmul_rn(h, 0.5f));
    const float x1 = __fadd_rn(cx, __fmul_rn(w, 0.5f));
    const float th = __fsub_rn(y1, y0), tw = __fsub_rn(x1, x0);
    o0 = (float)(cls + 1);
    o1 = __uint_as_float(sb);
    o2 = __fadd_rn(x0, __fmul_rn(tw, 0.5f));
    o3 = __fadd_rn(y0, __fmul_rn(th, 0.5f));
    o4 = tw;
    o5 = th;
  }
  if (isbf) {
    __hip_bfloat16* op = (__hip_bfloat16*)outv + ((size_t)b * NK + tid) * 6;
    op[0] = __float2bfloat16(o0); op[1] = __float2bfloat16(o1);
    op[2] = __float2bfloat16(o2); op[3] = __float2bfloat16(o3);
    op[4] = __float2bfloat16(o4); op[5] = __float2bfloat16(o5);
  } else {
    float* op = (float*)outv + ((size_t)b * NK + tid) * 6;
    op[0] = o0; op[1] = o1; op[2] = o2; op[3] = o3; op[4] = o4; op[5] = o5;
  }
}

// per batch: sort <=512 collected entries, emit top-200 (radix fallback if overflow)
__global__ __launch_bounds__(1024) void k_out(const void* __restrict__ inv,
                                              const u32* __restrict__ meta,
                                              const u64* __restrict__ list,
                                              const u32* __restrict__ selcnt,
                                              const u64* __restrict__ selbuf,
                                              void* __restrict__ outv) {
  const int b = blockIdx.x, tid = threadIdx.x, lane = tid & 63, wid = tid >> 6;
  const u32 isbf = meta[0];
  const u64* lb = list + (size_t)b * MT;

  __shared__ u64 sel[512];
  __shared__ u32 wsum[16];
  __shared__ u32 sh_cc;

  const u32 cc0 = selcnt[b];
  if (cc0 <= 512) {
    if (tid < 512) sel[tid] = (tid < (int)cc0) ? selbuf[(size_t)b * 512 + tid] : 0;
    __syncthreads();
  } else {
    // pathological overflow: exact radix fallback over the full list
    if (tid == 0) sh_cc = 0;
    __syncthreads();
    auto bsum = [&](u32 v) -> u32 {
#pragma unroll
      for (int off = 32; off > 0; off >>= 1) v += __shfl_down(v, off, 64);
      if (lane == 0) wsum[wid] = v;
      __syncthreads();
      u32 t = 0;
#pragma unroll
      for (int wq = 0; wq < 16; ++wq) t += wsum[wq];
      __syncthreads();
      return t;
    };
    u64 T = 0;
#pragma unroll 1
    for (int bit = 47; bit >= 0; --bit) {
      if (isbf && bit >= 18 && bit < 34) continue;
      const u64 T2 = T | (1ull << bit);
      u32 cn = 0;
      for (u32 i = tid; i < (u32)MT; i += 1024) {
        const u64 e = lb[i];
        cn += (e != 0 && (e >> 14) >= T2) ? 1u : 0u;
      }
      if (bsum(cn) >= (u32)NK) T = T2;
    }
    for (u32 i = tid; i < (u32)MT; i += 1024) {
      const u64 e = lb[i];
      if (e != 0 && (e >> 14) >= T) {
        const u32 p = atomicAdd(&sh_cc, 1u);
        if (p < 512) sel[p] = e;
      }
    }
    __syncthreads();
    const u32 cc = sh_cc;
    for (u32 p = cc + tid; p < 512; p += 1024) sel[p] = 0;
    __syncthreads();
  }

#pragma unroll 1
  for (u32 ks = 2; ks <= 512; ks <<= 1) {
#pragma unroll 1
    for (u32 j = ks >> 1; j > 0; j >>= 1) {
      if (tid < 512) {
        const u32 i = (u32)tid, ixj = i ^ j;
        if (ixj > i) {
          const u64 a = sel[i], c2 = sel[ixj];
          const bool up = ((i & ks) == 0);
          if (up ? (a > c2) : (a < c2)) { sel[i] = c2; sel[ixj] = a; }
        }
      }
      __syncthreads();
    }
  }

  if (tid < NK) emit_row(inv, isbf, b, tid, sel[511 - tid], outv);
}

extern "C" void kernel_launch(void* const* d_in, const int* in_sizes, int n_in,
                              void* d_out, int out_size, void* d_ws, size_t ws_size,
                              hipStream_t stream) {
  (void)in_sizes; (void)n_in; (void)out_size;
  const void* in = d_in[0];
  char* ws = (char*)d_ws;

  // layout: meta u32[8] @0 (32) | hist u32[2*4096] @32 (32,768) ->32,800
  //         cand/list u64[2*MT] @32,800 (2,875,200) ->2,908,000
  //         keysT u32[2*NC*NA] @2,908,000 (41,843,744) ->44,751,744
  //         selcnt/selbuf OVERLAY keysT @2,908,000 (64 + 8,192): keysT is dead after
  //         k_select; selcnt zeroed by k_thresh (post-select) -> timeline-safe.
  u32* meta   = (u32*)ws;
  u32* hist   = (u32*)(ws + 32);
  u64* candws = (u64*)(ws + 32800);
  u32* keysT  = (u32*)(ws + 2908000);
  u32* selcnt = (u32*)(ws + 2908000);
  u64* selbuf = (u64*)(ws + 2908064);
  const bool tier1 = ws_size >= 44751744u;   // coalesced key transpose enabled

  hipLaunchKernelGGL(k_detect, dim3(1), dim3(256), 0, stream, (const u16*)in, meta, hist);
  if (tier1) {
    hipLaunchKernelGGL(k_transpose_keys, dim3(10, 137, 2), dim3(256), 0, stream,
                       in, meta, keysT);
  }
  hipLaunchKernelGGL(k_select, dim3(NB * NC), dim3(256), 0, stream,
                     in, meta, candws, keysT, tier1 ? 1 : 0);
  hipLaunchKernelGGL(k_nms, dim3(NB * NC), dim3(64), 0, stream,
                     in, meta, candws, hist);
  hipLaunchKernelGGL(k_thresh, dim3(1), dim3(1024), 0, stream, hist, meta, selcnt);
  hipLaunchKernelGGL(k_collect, dim3((NB * MT + 255) / 256), dim3(256), 0, stream,
                     candws, meta, selcnt, selbuf);
  hipLaunchKernelGGL(k_out, dim3(NB), dim3(1024), 0, stream,
                     in, meta, candws, selcnt, selbuf, d_out);
}

// Round 9
// 265.462 us; speedup vs baseline: 7.3906x; 1.0391x over previous
//
#include <hip/hip_runtime.h>
#include <hip/hip_bf16.h>
#include <stdint.h>

typedef unsigned short u16;
typedef uint32_t u32;
typedef uint64_t u64;

#define NB 2
#define NA 8732
#define ND 604
#define NC 599
#define NM 300
#define NK 200
#define MT (NC * NM)     // 179700
#define NA4 (NA / 4)     // 2183
#define CONF 0.01f
#define NBIN 4096

#define T_PRESET (0xFull << 40)

__device__ __forceinline__ float bf2f(u16 u) { return __uint_as_float(((u32)u) << 16); }

// global top-k bin: fine resolution near s=1 (kept scores concentrate in (0.966,1)).
// bin ASCENDS as score DESCENDS.
__device__ __forceinline__ u32 binTop(u32 sbits) {
  const float t = __fsub_rn(1.0f, __uint_as_float(sbits));
  const float u = __fmul_rn(t, 65536.0f);
  u32 bin = (u32)u;
  return bin > (NBIN - 1) ? (NBIN - 1) : bin;
}

// per-class coarse score bin (ascending in score)
__device__ __forceinline__ u32 bin8(u32 kbits) {
  u32 bin = (u32)__fmul_rn(__uint_as_float(kbits), 256.0f);
  return bin > 255 ? 255 : bin;
}

// meta[0] = input storage is true-bf16. Also zeroes the per-batch score histogram.
__global__ void k_detect(const u16* __restrict__ in, u32* __restrict__ meta,
                         u32* __restrict__ hist) {
  __shared__ u32 ws4[4], wz4[4];
  const int tid = threadIdx.x, lane = tid & 63, wid = tid >> 6;
  u32 ct = 0, cz = 0;
  for (int i = tid; i < 8192; i += 256) {
    const u16 v = in[i];
    ct += (u32)(v >> 15);
    cz += (u32)(((i & 1) == 0) && (v == 0));
  }
  for (int i = tid; i < NB * NBIN; i += 256) hist[i] = 0u;
#pragma unroll
  for (int off = 32; off > 0; off >>= 1) {
    ct += __shfl_down(ct, off, 64);
    cz += __shfl_down(cz, off, 64);
  }
  if (lane == 0) { ws4[wid] = ct; wz4[wid] = cz; }
  __syncthreads();
  if (tid == 0) {
    const u32 tot_top = ws4[0] + ws4[1] + ws4[2] + ws4[3];
    const u32 tot_evz = wz4[0] + wz4[1] + wz4[2] + wz4[3];
    meta[0] = (tot_top == 0 && tot_evz < 1024) ? 1u : 0u;  // else f32 storage
    meta[1] = 0u; meta[2] = 0u; meta[3] = 0u;
  }
}

// tiled transpose of class scores -> thresholded u32 keys [b][c][n]
__global__ __launch_bounds__(256) void k_transpose_keys(const void* __restrict__ inv,
                                                        const u32* __restrict__ meta,
                                                        u32* __restrict__ keysT) {
  __shared__ u32 tile[64][65];
  const u32 isbf = meta[0];
  const int c0 = blockIdx.x * 64, n0 = blockIdx.y * 64, b = blockIdx.z;
  const int tj = threadIdx.x & 63, t4 = threadIdx.x >> 6;
  const u16* inh = (const u16*)inv;
  const float* inf_ = (const float*)inv;
#pragma unroll
  for (int kk = 0; kk < 16; ++kk) {
    const int i = t4 + kk * 4;
    const int n = n0 + i, c = c0 + tj;
    u32 kx = 0;
    if (n < NA && c < NC) {
      const size_t idx = (size_t)(b * NA + n) * ND + 1 + c;
      const float f = isbf ? bf2f(inh[idx]) : inf_[idx];
      kx = (f > CONF) ? __float_as_uint(f) : 0u;
    }
    tile[i][tj] = kx;
  }
  __syncthreads();
#pragma unroll
  for (int kk = 0; kk < 16; ++kk) {
    const int j = t4 + kk * 4;
    const int c = c0 + j, n = n0 + tj;
    if (c < NC && n < NA) keysT[(size_t)(b * NC + c) * NA + n] = tile[tj][j];
  }
}

// per-(b,c): exact stable top-300 via LDS-histogram superset + full-composite bitonic
// sort (radix fallback only if superset > 512). Writes the 300 sorted (descending)
// composites ((key<<14)|(16383-n)) to candws[bc*300 + rank]. NO NMS here.
__global__ __launch_bounds__(256) void k_select(const void* __restrict__ inv,
                                                const u32* __restrict__ meta,
                                                u64* __restrict__ candws,
                                                const u32* __restrict__ keysT,
                                                const int use_keys) {
  const int bc = blockIdx.x;
  const int b = bc / NC;
  const int c = bc - b * NC;
  const int tid = threadIdx.x;
  const int lane = tid & 63;
  const int wid = tid >> 6;

  __shared__ u32 wsum[4];
  __shared__ u64 cand[512];
  __shared__ u32 shist[256];
  __shared__ u32 sh_cnt, sh_B;

  const u32 isbf = meta[0];

  u32 key[36];
  if (use_keys) {
    const uint4* col4 = (const uint4*)(keysT + (size_t)(b * NC + c) * NA);
#pragma unroll
    for (int r = 0; r < 9; ++r) {
      const int i4 = r * 256 + tid;
      if (i4 < NA4) {
        const uint4 k4 = col4[i4];
        key[r * 4 + 0] = k4.x; key[r * 4 + 1] = k4.y;
        key[r * 4 + 2] = k4.z; key[r * 4 + 3] = k4.w;
      } else {
        key[r * 4 + 0] = 0; key[r * 4 + 1] = 0; key[r * 4 + 2] = 0; key[r * 4 + 3] = 0;
      }
    }
  } else if (isbf) {
    const u16* basep = (const u16*)inv + (size_t)b * NA * ND + 1 + c;
#pragma unroll
    for (int r = 0; r < 9; ++r) {
      const int i4 = r * 256 + tid;
#pragma unroll
      for (int kk = 0; kk < 4; ++kk) {
        u32 kx = 0;
        if (i4 < NA4) {
          const float f = bf2f(basep[(size_t)(i4 * 4 + kk) * ND]);
          kx = (f > CONF) ? __float_as_uint(f) : 0u;
        }
        key[r * 4 + kk] = kx;
      }
    }
  } else {
    const float* basep = (const float*)inv + (size_t)b * NA * ND + 1 + c;
#pragma unroll
    for (int r = 0; r < 9; ++r) {
      const int i4 = r * 256 + tid;
#pragma unroll
      for (int kk = 0; kk < 4; ++kk) {
        u32 kx = 0;
        if (i4 < NA4) {
          const float f = basep[(size_t)(i4 * 4 + kk) * ND];
          kx = (f > CONF) ? __float_as_uint(f) : 0u;
        }
        key[r * 4 + kk] = kx;
      }
    }
  }

  // LDS histogram over coarse score bins; threshold bin B with cum >= 300
  shist[tid] = 0;
  if (tid == 0) { sh_cnt = 0; sh_B = 0; }
  cand[tid] = 0; cand[tid + 256] = 0;
  __syncthreads();
#pragma unroll
  for (int e = 0; e < 36; ++e) atomicAdd(&shist[bin8(key[e])], 1u);
  __syncthreads();
  if (tid == 0) {
    u32 acc = 0, B = 0;
    for (int t = 255; t >= 0; --t) {
      acc += shist[t];
      if (acc >= (u32)NM) { B = (u32)t; break; }
    }
    sh_B = B;
  }
  __syncthreads();
  const u32 B = sh_B;

  // superset collect (score dominates composite ordering => contains all top-300)
#pragma unroll
  for (int r = 0; r < 9; ++r) {
#pragma unroll
    for (int kk = 0; kk < 4; ++kk) {
      const u32 k = key[r * 4 + kk];
      if (bin8(k) >= B) {
        const u32 nn = 16383u - (u32)((r * 256 + tid) * 4 + kk);
        const u32 p = atomicAdd(&sh_cnt, 1u);
        if (p < 512) cand[p] = (((u64)k) << 14) | (u64)nn;
      }
    }
  }
  __syncthreads();

  if (sh_cnt > 512) {
    // fallback: exact radix for the 300th composite, then exact collect
    auto blockSum = [&](u32 v) -> u32 {
#pragma unroll
      for (int off = 32; off > 0; off >>= 1) v += __shfl_down(v, off, 64);
      if (lane == 0) wsum[wid] = v;
      __syncthreads();
      const u32 tot = wsum[0] + wsum[1] + wsum[2] + wsum[3];
      __syncthreads();
      return tot;
    };
    u64 T = T_PRESET;
#pragma unroll 1
    for (int bit = 39; bit >= 0; --bit) {
      if (isbf && bit >= 14 && bit < 30) continue;
      const u64 T2 = T | (1ull << bit);
      const u32 Thi = (u32)(T2 >> 14);
      const u32 Tlo = (u32)(T2 & 0x3FFFu);
      u32 cnt = 0;
#pragma unroll
      for (int r = 0; r < 9; ++r) {
#pragma unroll
        for (int kk = 0; kk < 4; ++kk) {
          const u32 k = key[r * 4 + kk];
          const u32 nn = 16383u - (u32)((r * 256 + tid) * 4 + kk);
          cnt += (k > Thi || (k == Thi && nn >= Tlo)) ? 1u : 0u;
        }
      }
      if (blockSum(cnt) >= NM) T = T2;
    }
    if (tid == 0) sh_cnt = 0;
    cand[tid] = 0; cand[tid + 256] = 0;
    __syncthreads();
    const u32 Thi = (u32)(T >> 14);
    const u32 Tlo = (u32)(T & 0x3FFFu);
#pragma unroll
    for (int r = 0; r < 9; ++r) {
#pragma unroll
      for (int kk = 0; kk < 4; ++kk) {
        const u32 k = key[r * 4 + kk];
        const u32 nn = 16383u - (u32)((r * 256 + tid) * 4 + kk);
        if (k > Thi || (k == Thi && nn >= Tlo)) {
          const u32 p = atomicAdd(&sh_cnt, 1u);
          if (p < 512) cand[p] = (((u64)k) << 14) | (u64)nn;
        }
      }
    }
    __syncthreads();
  }

  // bitonic ascending sort; top-300 land at 511..212
#pragma unroll 1
  for (u32 ks = 2; ks <= 512; ks <<= 1) {
#pragma unroll 1
    for (u32 j = ks >> 1; j > 0; j >>= 1) {
#pragma unroll
      for (int rep = 0; rep < 2; ++rep) {
        const u32 i = tid + rep * 256;
        const u32 ixj = i ^ j;
        if (ixj > i) {
          const u64 a = cand[i], bb = cand[ixj];
          const bool up = ((i & ks) == 0);
          if (up ? (a > bb) : (a < bb)) { cand[i] = bb; cand[ixj] = a; }
        }
      }
      __syncthreads();
    }
  }

  // write descending top-300 composites
  u64* cw = candws + (size_t)bc * NM;
  if (tid < NM) cw[tid] = cand[511 - tid];
  if (tid < NM - 256) cw[256 + tid] = cand[511 - 256 - tid];
}

// one wave per (b,c): BALLOT-SKIP greedy NMS over the 300 sorted candidates.
// Greedy invariant: a suppressed candidate can never become a keeper, so we jump
// straight to the next unsuppressed candidate (ballot+ffs) instead of stepping all
// 300 slots -- the serial dependent chain shrinks from 300 to #keepers iterations.
// Suppression order/arithmetic identical to the reference (bit-exact).
__global__ __launch_bounds__(64) void k_nms(const void* __restrict__ inv,
                                            const u32* __restrict__ meta,
                                            u64* __restrict__ candws,
                                            u32* __restrict__ hist) {
  const int bc = blockIdx.x;
  const int b = bc / NC;
  const int c = bc - b * NC;
  const int lane = threadIdx.x;
  const u32 isbf = meta[0];
  u64* cw = candws + (size_t)bc * NM;

  float by0[5], bx0[5], by1[5], bx1[5], bar[5], bv[5];
  u32 bn[5];
  bool sup[5], keep[5];
#pragma unroll
  for (int q = 0; q < 5; ++q) {
    const int j = q * 64 + lane;
    keep[q] = false;
    by0[q] = bx0[q] = by1[q] = bx1[q] = bar[q] = 0.f;
    if (j < NM) {
      const u64 e = cw[j];
      const u32 sb = (u32)(e >> 14);
      u32 n = 16383u - ((u32)e & 0x3FFFu);
      if (n >= (u32)NA) n = 0;      // zero-pad slot
      sup[q] = false;
      bn[q] = n;
      bv[q] = __uint_as_float(sb);  // 0.0f for pad/below-conf
      float cx, cy, w, h;
      if (isbf) {
        const u16* bp = (const u16*)inv + (size_t)(b * NA + n) * ND + 600;
        const ushort4 ub = *(const ushort4*)bp;
        cx = bf2f(ub.x); cy = bf2f(ub.y); w = bf2f(ub.z); h = bf2f(ub.w);
      } else {
        const float* bp = (const float*)inv + (size_t)(b * NA + n) * ND + 600;
        const float4 f4 = *(const float4*)bp;
        cx = f4.x; cy = f4.y; w = f4.z; h = f4.w;
      }
      const float y0 = __fsub_rn(cy, __fmul_rn(h, 0.5f));
      const float x0 = __fsub_rn(cx, __fmul_rn(w, 0.5f));
      const float y1 = __fadd_rn(cy, __fmul_rn(h, 0.5f));
      const float x1 = __fadd_rn(cx, __fmul_rn(w, 0.5f));
      by0[q] = y0; bx0[q] = x0; by1[q] = y1; bx1[q] = x1;
      bar[q] = __fmul_rn(__fsub_rn(y1, y0), __fsub_rn(x1, x0));
    } else {
      bv[q] = 0.f; bn[q] = 0; sup[q] = true;
    }
  }

#pragma unroll
  for (int qi = 0; qi < 5; ++qi) {
    const int lim = (qi == 4) ? (NM - 256) : 64;   // 44 on the last chunk
    const bool inlim = (lane < lim);
    const bool conf_ok = (bv[qi] > CONF);
    int p = 0;
#pragma unroll 1
    while (true) {
      // next unsuppressed, above-conf candidate at position >= p in this chunk
      const bool el = inlim && conf_ok && !sup[qi] && (lane >= p);
      const u64 m = __ballot(el);
      if (m == 0) break;
      const int li = (int)(__ffsll((unsigned long long)m)) - 1;  // keeper (wave-uniform)
      if (lane == li) keep[qi] = true;
      const float iy0 = __shfl(by0[qi], li, 64);
      const float ix0 = __shfl(bx0[qi], li, 64);
      const float iy1 = __shfl(by1[qi], li, 64);
      const float ix1 = __shfl(bx1[qi], li, 64);
      const float iar = __shfl(bar[qi], li, 64);
      const int i = qi * 64 + li;
#pragma unroll
      for (int q = 0; q < 5; ++q) {
        if (q >= qi) {    // chunks before qi have j < i
          const int j = q * 64 + lane;
          if (j > i && j < NM && !sup[q]) {
            const float ih = fmaxf(__fsub_rn(fminf(iy1, by1[q]), fmaxf(iy0, by0[q])), 0.f);
            const float iw = fmaxf(__fsub_rn(fminf(ix1, bx1[q]), fmaxf(ix0, bx0[q])), 0.f);
            const float inter = __fmul_rn(ih, iw);
            const float uni = __fsub_rn(__fadd_rn(iar, bar[q]), inter);
            if (uni > 0.f && __fdiv_rn(inter, uni) > 0.45f) sup[q] = true;
          }
        }
      }
      p = li + 1;
    }
  }

  // in-place write-back (block owns its slice; reads happened above)
#pragma unroll
  for (int q = 0; q < 5; ++q) {
    const int j = q * 64 + lane;
    if (j < NM) {
      u64 entry = 0;
      if (keep[q]) {
        const u32 sb = __float_as_uint(bv[q]);
        const u32 flat = (u32)c * NM + (u32)j;
        entry = (((u64)sb) << 32) | (((u64)(0x3FFFFu - flat)) << 14) | (u64)bn[q];
        atomicAdd(&hist[(size_t)b * NBIN + binTop(sb)], 1u);
      }
      cw[j] = entry;
    }
  }
}

// compute per-batch bin threshold B (cum >= 200 scanning from highest scores);
// also zero the collect counters (safe here: keysT is dead after k_select).
__global__ __launch_bounds__(1024) void k_thresh(const u32* __restrict__ hist,
                                                 u32* __restrict__ meta,
                                                 u32* __restrict__ selcnt) {
  __shared__ u32 ps[1024];
  const int tid = threadIdx.x;
  if (tid < NB) selcnt[tid] = 0;
  for (int b = 0; b < NB; ++b) {
    const u32* hh = hist + (size_t)b * NBIN;
    const uint4 hv = ((const uint4*)hh)[tid];
    ps[tid] = hv.x + hv.y + hv.z + hv.w;
    __syncthreads();
    if (tid == 0) {
      u32 acc = 0, B = (u32)(NBIN - 1);
      for (int t = 0; t < 1024; ++t) {
        if (acc + ps[t] >= (u32)NK) {
          u32 a2 = acc;
          for (int jj = 0; jj < 4; ++jj) {
            const u32 cb = hh[t * 4 + jj];
            if (a2 + cb >= (u32)NK) { B = (u32)(t * 4 + jj); break; }
            a2 += cb;
          }
          break;
        }
        acc += ps[t];
      }
      meta[4 + b] = B;   // never reached 200 => NBIN-1 => collect everything
    }
    __syncthreads();
  }
}

// full-chip scan of the kept list; append qualifying entries (~250/batch)
__global__ __launch_bounds__(256) void k_collect(const u64* __restrict__ list,
                                                 const u32* __restrict__ meta,
                                                 u32* __restrict__ selcnt,
                                                 u64* __restrict__ selbuf) {
  const u32 i = blockIdx.x * 256 + threadIdx.x;
  if (i >= (u32)(NB * MT)) return;
  const u32 b = (i < (u32)MT) ? 0u : 1u;
  const u64 e = list[i];
  if (e != 0 && binTop((u32)(e >> 32)) <= meta[4 + b]) {
    const u32 p = atomicAdd(&selcnt[b], 1u);
    if (p < 512) selbuf[(size_t)b * 512 + p] = e;
  }
}

// shared epilogue: corner->center transform + dtype-matched store
__device__ __forceinline__ void emit_row(const void* inv, u32 isbf, int b, int tid,
                                         u64 e, void* outv) {
  float o0 = 0, o1 = 0, o2 = 0, o3 = 0, o4 = 0, o5 = 0;
  if (e != 0) {
    const u32 sb = (u32)(e >> 32);
    const u32 flat = 0x3FFFFu - ((u32)(e >> 14) & 0x3FFFFu);
    const u32 anchor = (u32)e & 0x3FFFu;
    const u32 cls = flat / NM;
    float cx, cy, w, h;
    if (isbf) {
      const u16* bp = (const u16*)inv + (size_t)(b * NA + anchor) * ND + 600;
      const ushort4 ub = *(const ushort4*)bp;
      cx = bf2f(ub.x); cy = bf2f(ub.y); w = bf2f(ub.z); h = bf2f(ub.w);
    } else {
      const float* bp = (const float*)inv + (size_t)(b * NA + anchor) * ND + 600;
      const float4 f4 = *(const float4*)bp;
      cx = f4.x; cy = f4.y; w = f4.z; h = f4.w;
    }
    const float y0 = __fsub_rn(cy, __fmul_rn(h, 0.5f));
    const float x0 = __fsub_rn(cx, __fmul_rn(w, 0.5f));
    const float y1 = __fadd_rn(cy, __fmul_rn(h, 0.5f));
    const float x1 = __fadd_rn(cx, __fmul_rn(w, 0.5f));
    const float th = __fsub_rn(y1, y0), tw = __fsub_rn(x1, x0);
    o0 = (float)(cls + 1);
    o1 = __uint_as_float(sb);
    o2 = __fadd_rn(x0, __fmul_rn(tw, 0.5f));
    o3 = __fadd_rn(y0, __fmul_rn(th, 0.5f));
    o4 = tw;
    o5 = th;
  }
  if (isbf) {
    __hip_bfloat16* op = (__hip_bfloat16*)outv + ((size_t)b * NK + tid) * 6;
    op[0] = __float2bfloat16(o0); op[1] = __float2bfloat16(o1);
    op[2] = __float2bfloat16(o2); op[3] = __float2bfloat16(o3);
    op[4] = __float2bfloat16(o4); op[5] = __float2bfloat16(o5);
  } else {
    float* op = (float*)outv + ((size_t)b * NK + tid) * 6;
    op[0] = o0; op[1] = o1; op[2] = o2; op[3] = o3; op[4] = o4; op[5] = o5;
  }
}

// per batch: sort <=512 collected entries, emit top-200 (radix fallback if overflow)
__global__ __launch_bounds__(1024) void k_out(const void* __restrict__ inv,
                                              const u32* __restrict__ meta,
                                              const u64* __restrict__ list,
                                              const u32* __restrict__ selcnt,
                                              const u64* __restrict__ selbuf,
                                              void* __restrict__ outv) {
  const int b = blockIdx.x, tid = threadIdx.x, lane = tid & 63, wid = tid >> 6;
  const u32 isbf = meta[0];
  const u64* lb = list + (size_t)b * MT;

  __shared__ u64 sel[512];
  __shared__ u32 wsum[16];
  __shared__ u32 sh_cc;

  const u32 cc0 = selcnt[b];
  if (cc0 <= 512) {
    if (tid < 512) sel[tid] = (tid < (int)cc0) ? selbuf[(size_t)b * 512 + tid] : 0;
    __syncthreads();
  } else {
    // pathological overflow: exact radix fallback over the full list
    if (tid == 0) sh_cc = 0;
    __syncthreads();
    auto bsum = [&](u32 v) -> u32 {
#pragma unroll
      for (int off = 32; off > 0; off >>= 1) v += __shfl_down(v, off, 64);
      if (lane == 0) wsum[wid] = v;
      __syncthreads();
      u32 t = 0;
#pragma unroll
      for (int wq = 0; wq < 16; ++wq) t += wsum[wq];
      __syncthreads();
      return t;
    };
    u64 T = 0;
#pragma unroll 1
    for (int bit = 47; bit >= 0; --bit) {
      if (isbf && bit >= 18 && bit < 34) continue;
      const u64 T2 = T | (1ull << bit);
      u32 cn = 0;
      for (u32 i = tid; i < (u32)MT; i += 1024) {
        const u64 e = lb[i];
        cn += (e != 0 && (e >> 14) >= T2) ? 1u : 0u;
      }
      if (bsum(cn) >= (u32)NK) T = T2;
    }
    for (u32 i = tid; i < (u32)MT; i += 1024) {
      const u64 e = lb[i];
      if (e != 0 && (e >> 14) >= T) {
        const u32 p = atomicAdd(&sh_cc, 1u);
        if (p < 512) sel[p] = e;
      }
    }
    __syncthreads();
    const u32 cc = sh_cc;
    for (u32 p = cc + tid; p < 512; p += 1024) sel[p] = 0;
    __syncthreads();
  }

#pragma unroll 1
  for (u32 ks = 2; ks <= 512; ks <<= 1) {
#pragma unroll 1
    for (u32 j = ks >> 1; j > 0; j >>= 1) {
      if (tid < 512) {
        const u32 i = (u32)tid, ixj = i ^ j;
        if (ixj > i) {
          const u64 a = sel[i], c2 = sel[ixj];
          const bool up = ((i & ks) == 0);
          if (up ? (a > c2) : (a < c2)) { sel[i] = c2; sel[ixj] = a; }
        }
      }
      __syncthreads();
    }
  }

  if (tid < NK) emit_row(inv, isbf, b, tid, sel[511 - tid], outv);
}

extern "C" void kernel_launch(void* const* d_in, const int* in_sizes, int n_in,
                              void* d_out, int out_size, void* d_ws, size_t ws_size,
                              hipStream_t stream) {
  (void)in_sizes; (void)n_in; (void)out_size;
  const void* in = d_in[0];
  char* ws = (char*)d_ws;

  // layout: meta u32[8] @0 (32) | hist u32[2*4096] @32 (32,768) ->32,800
  //         cand/list u64[2*MT] @32,800 (2,875,200) ->2,908,000
  //         keysT u32[2*NC*NA] @2,908,000 (41,843,744) ->44,751,744
  //         selcnt/selbuf OVERLAY keysT @2,908,000: keysT dead after k_select;
  //         selcnt zeroed by k_thresh (post-select) -> timeline-safe.
  u32* meta   = (u32*)ws;
  u32* hist   = (u32*)(ws + 32);
  u64* candws = (u64*)(ws + 32800);
  u32* keysT  = (u32*)(ws + 2908000);
  u32* selcnt = (u32*)(ws + 2908000);
  u64* selbuf = (u64*)(ws + 2908064);
  const bool tier1 = ws_size >= 44751744u;   // coalesced key transpose enabled

  hipLaunchKernelGGL(k_detect, dim3(1), dim3(256), 0, stream, (const u16*)in, meta, hist);
  if (tier1) {
    hipLaunchKernelGGL(k_transpose_keys, dim3(10, 137, 2), dim3(256), 0, stream,
                       in, meta, keysT);
  }
  hipLaunchKernelGGL(k_select, dim3(NB * NC), dim3(256), 0, stream,
                     in, meta, candws, keysT, tier1 ? 1 : 0);
  hipLaunchKernelGGL(k_nms, dim3(NB * NC), dim3(64), 0, stream,
                     in, meta, candws, hist);
  hipLaunchKernelGGL(k_thresh, dim3(1), dim3(1024), 0, stream, hist, meta, selcnt);
  hipLaunchKernelGGL(k_collect, dim3((NB * MT + 255) / 256), dim3(256), 0, stream,
                     candws, meta, selcnt, selbuf);
  hipLaunchKernelGGL(k_out, dim3(NB), dim3(1024), 0, stream,
                     in, meta, candws, selcnt, selbuf, d_out);
}